// Round 11
// baseline (217.319 us; speedup 1.0000x reference)
//
#include <hip/hip_runtime.h>
#include <stdint.h>

typedef float f32x4 __attribute__((ext_vector_type(4)));
typedef short s16x8 __attribute__((ext_vector_type(8)));
typedef short s16x4 __attribute__((ext_vector_type(4)));

__device__ __forceinline__ short f2bf(float f){
  union { float f; unsigned u; } v; v.f = f;
  unsigned r = v.u + 0x7FFFu + ((v.u >> 16) & 1u);
  return (short)(r >> 16);
}
__device__ __forceinline__ float bf2f(short h){
  union { unsigned u; float f; } v; v.u = ((unsigned)(unsigned short)h) << 16;
  return v.f;
}

// ---------- fused prep: addcvt (blocks 0..8191), cvt x3 (8192..11263),
// transcvt x3 (11264..14335), bias1 (14336..14847) ----------
__global__ void k_prep(const float* __restrict__ ta, const float* __restrict__ tb,
                       short* __restrict__ so,
                       const float* __restrict__ c0s, short* __restrict__ c0d,
                       const float* __restrict__ c1s, short* __restrict__ c1d,
                       const float* __restrict__ c2s, short* __restrict__ c2d,
                       const float* __restrict__ t0s, short* __restrict__ t0d,
                       const float* __restrict__ t1s, short* __restrict__ t1d,
                       const float* __restrict__ t2s, short* __restrict__ t2d,
                       const float* __restrict__ wt, const float* __restrict__ bvt, const float* __restrict__ obt,
                       const float* __restrict__ wi, const float* __restrict__ bvi, const float* __restrict__ obi,
                       float* __restrict__ bc){
  int bid = blockIdx.x;
  int tid = threadIdx.x;
  if (bid < 8192) {
    long i = (long)bid * 256 + tid;
    const f32x4* a4 = (const f32x4*)ta;
    const f32x4* b4 = (const f32x4*)tb;
    f32x4 x0 = a4[2*i], x1 = a4[2*i+1];
    f32x4 y0 = b4[2*i], y1 = b4[2*i+1];
    s16x8 r;
    #pragma unroll
    for (int j=0;j<4;j++){ r[j] = f2bf(x0[j]+y0[j]); r[j+4] = f2bf(x1[j]+y1[j]); }
    *(s16x8*)(so + i*8) = r;
    return;
  }
  bid -= 8192;
  if (bid < 3072) {
    int z = bid >> 10, b = bid & 1023;
    const float* in = (z==0) ? c0s : ((z==1) ? c1s : c2s);
    short* out      = (z==0) ? c0d : ((z==1) ? c1d : c2d);
    long i = (long)b*256 + tid;
    f32x4 v = ((const f32x4*)in)[i];
    s16x4 r;
    #pragma unroll
    for (int j=0;j<4;j++) r[j] = f2bf(v[j]);
    *(s16x4*)(out + i*4) = r;
  } else if (bid < 6144) {
    int q = bid - 3072;
    int z = q >> 10, b = q & 1023;
    const float* in = (z==0) ? t0s : ((z==1) ? t1s : t2s);
    short* out      = (z==0) ? t0d : ((z==1) ? t1d : t2d);
    __shared__ float tile[32][33];
    int tx = tid & 31, ty = tid >> 5;
    int c0 = (b & 31)*32, r0 = (b >> 5)*32;
    #pragma unroll
    for (int i=ty; i<32; i+=8)
      tile[i][tx] = in[(long)(r0+i)*1024 + c0 + tx];
    __syncthreads();
    #pragma unroll
    for (int i=ty; i<32; i+=8)
      out[(long)(c0+i)*1024 + r0 + tx] = f2bf(tile[tx][i]);
  } else {
    int q = bid - 6144;
    int z = q >> 8, b = q & 255;
    const float* w  = z ? wi  : wt;
    const float* bv = z ? bvi : bvt;
    const float* ob = z ? obi : obt;
    int n = b*4 + (tid>>6);
    int lane = tid & 63;
    const float* row = w + (long)n*1024;
    float acc = 0.f;
    for (int j=lane; j<1024; j+=64) acc += row[j]*bv[j];
    #pragma unroll
    for (int m=32;m;m>>=1) acc += __shfl_xor(acc, m, 64);
    if (lane==0) bc[z*1024+n] = acc + ob[n];
  }
}

#define GLDS(src, dst) __builtin_amdgcn_global_load_lds( \
    (const __attribute__((address_space(1))) void*)(src), \
    (__attribute__((address_space(3))) void*)(dst), 16, 0, 0)

// ---------- small NT GEMM body (128x128 tile, m97 structure): C bf16 = A@B^T ----------
__device__ __forceinline__
void gemm_small_body(const short* __restrict__ A, const short* __restrict__ B,
                     short* __restrict__ C, int N, int K, int m0, int n0,
                     short* ldsA, short* ldsB, int tid)
{
  const int lane = tid & 63;
  const int wv = tid >> 6;
  const int wm = wv >> 1, wn = wv & 1;

  f32x4 acc[4][4];
  #pragma unroll
  for (int i=0;i<4;i++)
    #pragma unroll
    for (int j=0;j<4;j++) acc[i][j] = (f32x4){0.f,0.f,0.f,0.f};

  const int bo0 = wv*1024 + lane*16;
  const int bo1 = bo0 + 4096;
  const int r0 = bo0 >> 6, c0 = bo0 & 63;
  const int r1 = bo1 >> 6, c1 = bo1 & 63;
  const long rsb = (long)K * 2;

  const char* Ab = (const char*)A;
  const char* Bb = (const char*)B;
  char* lA = (char*)ldsA;
  char* lB = (char*)ldsB;

  const int nkt = K >> 5;
  for (int kt = 0; kt < nkt; ++kt) {
    const long kb = (long)kt * 64;
    GLDS(Ab + (long)(m0 + r0)*rsb + kb + c0, lA + wv*1024);
    GLDS(Ab + (long)(m0 + r1)*rsb + kb + c1, lA + 4096 + wv*1024);
    GLDS(Bb + (long)(n0 + r0)*rsb + kb + c0, lB + wv*1024);
    GLDS(Bb + (long)(n0 + r1)*rsb + kb + c1, lB + 4096 + wv*1024);
    __syncthreads();

    s16x8 af[4], bfv[4];
    #pragma unroll
    for (int i=0;i<4;i++)
      af[i] = *(const s16x8*)(lA + (wm*64 + i*16 + (lane&15))*64 + (lane>>4)*16);
    #pragma unroll
    for (int j=0;j<4;j++)
      bfv[j] = *(const s16x8*)(lB + (wn*64 + j*16 + (lane&15))*64 + (lane>>4)*16);

    #pragma unroll
    for (int i=0;i<4;i++)
      #pragma unroll
      for (int j=0;j<4;j++)
        acc[i][j] = __builtin_amdgcn_mfma_f32_16x16x32_bf16(af[i], bfv[j], acc[i][j], 0, 0, 0);
    __syncthreads();
  }

  #pragma unroll
  for (int j=0;j<4;j++){
    int gn = n0 + wn*64 + j*16 + (lane&15);
    #pragma unroll
    for (int i=0;i<4;i++){
      int gmb = m0 + wm*64 + i*16 + ((lane>>4)*4);
      #pragma unroll
      for (int r=0;r<4;r++)
        C[(long)(gmb+r)*N + gn] = f2bf(acc[i][j][r]);
    }
  }
}

// launch 2: Wc_z = out_w_z @ wv_z (z batches via blockIdx.z)
__global__ __launch_bounds__(256, 2)
void gemm_wc(const short* __restrict__ Abase, const short* __restrict__ Bbase,
             short* __restrict__ Cbase, long zA, long zB, long zC)
{
  __shared__ __align__(16) short ldsA[128*32];
  __shared__ __align__(16) short ldsB[128*32];
  gemm_small_body(Abase + (long)blockIdx.z*zA, Bbase + (long)blockIdx.z*zB,
                  Cbase + (long)blockIdx.z*zC, 1024, 1024,
                  blockIdx.x*128, blockIdx.y*128, ldsA, ldsB, threadIdx.x);
}

// launch 3 (merged): blocks 0..515 = bias2+copy; 516..643 = W2 = Wc @ fuse_w
__global__ __launch_bounds__(256, 2)
void k_b2g2(const short* __restrict__ Wc, const float* __restrict__ fuse_b,
            const float* __restrict__ bc, float* __restrict__ b_all,
            const short* __restrict__ fuse_wT, short* __restrict__ W2)
{
  __shared__ __align__(16) short ldsA[128*32];
  __shared__ __align__(16) short ldsB[128*32];
  int bid = blockIdx.x;
  if (bid < 512) {
    int n = bid*4 + (threadIdx.x>>6);
    int lane = threadIdx.x & 63;
    const short* row = Wc + (long)n*1024;
    float acc = 0.f;
    for (int j=lane; j<1024; j+=64) acc += bf2f(row[j])*fuse_b[j];
    #pragma unroll
    for (int m=32;m;m>>=1) acc += __shfl_xor(acc, m, 64);
    if (lane==0) b_all[1024+n] = acc + bc[n];
    return;
  }
  if (bid < 516) {
    int i = (bid - 512)*256 + threadIdx.x;
    b_all[i] = fuse_b[i];
    return;
  }
  int g = bid - 516;                 // 0..127 -> 16 x 8 tiles of 2048x1024
  gemm_small_body(Wc, fuse_wT, W2, 1024, 1024,
                  (g & 15)*128, (g >> 4)*128, ldsA, ldsB, threadIdx.x);
}

// ---------- main NT GEMM: 256x256, BK=64, DEEP-SLACK schedule (R11) ----------
// LDS: Abuf0 @0, Abuf1 @32768, Bbuf0 @65536, Bbuf1 @98304 (32 KB each).
// Swizzle: 16B-chunk s of row r stored at s^(r&7); conflict-free (verified: 0).
// Hypothesis under test: the shared ~30% plateau of R1-R10 is staging-latency
// exposure (1-phase slack < L3/HBM latency, no TLP at 1 block/CU). Both
// operands now get 2 FULL phases of drain slack:
//   ks0(t): read bfr=B(t) x8 + af=A(t,ks0) x8; barrier(A); LGKM0; 32 MFMA.
//   ks1(t): read af=A(t,ks1) x8; VMW0 [drains A(t+1),B(t+1) issued @(t-1,ks1)];
//           barrier(B); LGKM0 [own reads done]; barrier(C) [ALL waves' reads
//           done -> GLDS writes cannot race any read]; stage A(t+2)->Abuf[t&1]
//           + B(t+2)->Bbuf[t&1]; 32 MFMA.
// Read-safety: A(t)/B(t) issued @(t-2,ks1), drained @(t-1,ks1) VMW0, fenced by
// its barriers, first read @(t,ks0). Slack = 2 phases (~2400+ cyc) >= HBM miss.
// Write-safety: stage targets' last reads complete before barrier(C) (every
// wave's LGKM0 precedes it). 3 barriers + 1 VMW0 per K-tile (R7 had 4 + 2).
#define MFMA16 __builtin_amdgcn_mfma_f32_16x16x32_bf16
#define VMW0 asm volatile("s_waitcnt vmcnt(0)" ::: "memory")
#define LGKM0 asm volatile("s_waitcnt lgkmcnt(0)" ::: "memory")
#define MEMF asm volatile("" ::: "memory")

__global__ __launch_bounds__(512, 2)
void gemm_main(const short* __restrict__ A, const short* __restrict__ B,
               float* __restrict__ O, const float* __restrict__ bias,
               int M, int N, int K)
{
  __shared__ __align__(16) char lds[131072];

  const int nbn = N >> 8;
  const int nwg = (M >> 8) * nbn;
  const int cpx = nwg >> 3;
  int bid = blockIdx.x;
  int swz = (bid & 7) * cpx + (bid >> 3);
  const int m0 = (swz / nbn) << 8;
  const int n0 = (swz % nbn) << 8;

  const int tid  = threadIdx.x;
  const int lane = tid & 63;
  const int wid  = tid >> 6;
  const int wm   = wid >> 2;   // 0..1
  const int wn   = wid & 3;    // 0..3
  const long rsb = (long)K * 2;
  const char* Ab = (const char*)A;
  const char* Bb = (const char*)B;

  f32x4 acc[8][4];
  #pragma unroll
  for (int i=0;i<8;i++)
    #pragma unroll
    for (int j=0;j<4;j++) acc[i][j] = (f32x4){0.f,0.f,0.f,0.f};

  // Stage source precompute: linear LDS dest chunk c receives logical chunk
  // q = c ^ ((c>>3)&7)  (row preserved; inverse of the read swizzle).
  int srow[2][2]; int scol[2][2]; int sdst[2][2];
  #pragma unroll
  for (int H=0;H<2;H++)
    #pragma unroll
    for (int sb=0;sb<2;sb++){
      int c = H*1024 + sb*512 + wid*64 + lane;
      int q = c ^ ((c>>3)&7);
      srow[H][sb] = q >> 3;
      scol[H][sb] = (q & 7) << 4;
      sdst[H][sb] = (H*1024 + sb*512 + wid*64) << 4;
    }

  auto stage = [&](const char* P, int tr0, int s /*K-tile*/, int RB, int H){
    const long ktb = (long)s << 7;
    GLDS(P + ((long)(tr0 + srow[H][0]))*rsb + ktb + scol[H][0], lds + RB + sdst[H][0]);
    GLDS(P + ((long)(tr0 + srow[H][1]))*rsb + ktb + scol[H][1], lds + RB + sdst[H][1]);
  };

  const int swx = (lane & 7) << 4;   // read swizzle (row&7 == lane&7 for all frags)
  auto ldA = [&](int RB, int i, int ks) -> s16x8 {
    int off = (wm*128 + i*16 + (lane&15))*128 + ks*64 + ((lane>>4)<<4);
    off ^= swx;
    return *(const s16x8*)(lds + RB + off);
  };
  auto ldB = [&](int RB, int j, int ks) -> s16x8 {
    int off = (wn*64 + j*16 + (lane&15))*128 + ks*64 + ((lane>>4)<<4);
    off ^= swx;
    return *(const s16x8*)(lds + 65536 + RB + off);
  };

  s16x8 bfr[4][2];
  s16x8 af[8];
  const int nkt = K >> 6;  // 16 for K=1024

  // Prologue: stage A(0),B(0),A(1),B(1) (16 GLDS); full drain; barrier.
  stage(Ab, m0, 0, 0,     0); stage(Ab, m0, 0, 0,     1);
  stage(Bb, n0, 0, 65536, 0); stage(Bb, n0, 0, 65536, 1);
  stage(Ab, m0, 1, 32768, 0); stage(Ab, m0, 1, 32768, 1);
  stage(Bb, n0, 1, 98304, 0); stage(Bb, n0, 1, 98304, 1);
  VMW0; MEMF;
  __builtin_amdgcn_s_barrier();

  for (int t = 0; t < nkt; ++t) {
    const int RB = (t & 1) << 15;
    // -------- ks0 phase (no staging) --------
    #pragma unroll
    for (int j=0;j<4;j++){ bfr[j][0] = ldB(RB, j, 0); bfr[j][1] = ldB(RB, j, 1); }
    #pragma unroll
    for (int i=0;i<8;i++) af[i] = ldA(RB, i, 0);
    MEMF;
    __builtin_amdgcn_s_barrier();          // bar A
    LGKM0;
    __builtin_amdgcn_s_setprio(1);
    #pragma unroll
    for (int i=0;i<8;i++)
      #pragma unroll
      for (int j=0;j<4;j++)
        acc[i][j] = MFMA16(af[i], bfr[j][0], acc[i][j], 0, 0, 0);
    __builtin_amdgcn_s_setprio(0);
    // -------- ks1 phase (all staging, 2-phase slack) --------
    #pragma unroll
    for (int i=0;i<8;i++) af[i] = ldA(RB, i, 1);
    VMW0; MEMF;                            // drains A(t+1)+B(t+1) (issued @(t-1,ks1))
    __builtin_amdgcn_s_barrier();          // bar B
    LGKM0;                                 // own LDS reads complete
    MEMF;
    __builtin_amdgcn_s_barrier();          // bar C: ALL waves' reads complete
    if (t+2 < nkt) {
      stage(Ab, m0, t+2, RB, 0);          stage(Ab, m0, t+2, RB, 1);
      stage(Bb, n0, t+2, 65536 + RB, 0);  stage(Bb, n0, t+2, 65536 + RB, 1);
    }
    __builtin_amdgcn_s_setprio(1);
    #pragma unroll
    for (int i=0;i<8;i++)
      #pragma unroll
      for (int j=0;j<4;j++)
        acc[i][j] = MFMA16(af[i], bfr[j][1], acc[i][j], 0, 0, 0);
    __builtin_amdgcn_s_setprio(0);
  }

  // Epilogue: fp32 + bias, scatter by output region (text | image | fused).
  const long BD = (long)M * 1024L;
  #pragma unroll
  for (int j=0;j<4;j++){
    int gn = n0 + wn*64 + j*16 + (lane&15);
    float bb = bias[gn];
    int region = gn >> 10;
    long rbase = (region==0) ? 2*BD : ((region==1) ? 0L : BD);
    int col = gn & 1023;
    #pragma unroll
    for (int i=0;i<8;i++){
      int gr = m0 + wm*128 + i*16 + ((lane>>4)<<2);
      #pragma unroll
      for (int r=0;r<4;r++)
        O[rbase + (long)(gr+r)*1024 + col] = acc[i][j][r] + bb;
    }
  }
}

extern "C" void kernel_launch(void* const* d_in, const int* in_sizes, int n_in,
                              void* d_out, int out_size, void* d_ws, size_t ws_size,
                              hipStream_t stream) {
  const float* text    = (const float*)d_in[0];
  const float* image   = (const float*)d_in[1];
  const float* fuse_w  = (const float*)d_in[2];
  const float* fuse_b  = (const float*)d_in[3];
  const float* t_in_w  = (const float*)d_in[4];
  const float* t_in_b  = (const float*)d_in[5];
  const float* t_out_w = (const float*)d_in[6];
  const float* t_out_b = (const float*)d_in[7];
  const float* i_in_w  = (const float*)d_in[8];
  const float* i_in_b  = (const float*)d_in[9];
  const float* i_out_w = (const float*)d_in[10];
  const float* i_out_b = (const float*)d_in[11];
  float* out = (float*)d_out;

  const long DD = 1024L*1024L;
  char* ws = (char*)d_ws;
  short* s_bf    = (short*)ws; ws += 16384L*1024*2;
  short* W_all   = (short*)ws; ws += 3*DD*2;      // rows: [fuse_w; Wt2; Wi2]
  short* wvT     = (short*)ws; ws += 2*DD*2;      // [wvT_t; wvT_i]
  short* fuse_wT = (short*)ws; ws += DD*2;
  short* outw_st = (short*)ws; ws += 2*DD*2;      // [t_out_w; i_out_w] bf16
  short* Wc_st   = (short*)ws; ws += 2*DD*2;      // [Wc_t; Wc_i]
  float* bc      = (float*)ws; ws += 2048*4;
  float* b_all   = (float*)ws; ws += 3072*4;

  // launch 1: all elementwise prep (addcvt + cvt + transcvt + bias1)
  k_prep<<<14848, 256, 0, stream>>>(text, image, s_bf,
                                    fuse_w, W_all,
                                    t_out_w, outw_st,
                                    i_out_w, outw_st + DD,
                                    t_in_w + 2*DD, wvT,
                                    i_in_w + 2*DD, wvT + DD,
                                    fuse_w, fuse_wT,
                                    t_out_w, t_in_b + 2048, t_out_b,
                                    i_out_w, i_in_b + 2048, i_out_b, bc);

  // launch 2: Wc_z = out_w_z @ wv_z
  gemm_wc<<<dim3(8,8,2), 256, 0, stream>>>(outw_st, wvT, Wc_st, DD, DD, DD);

  // launch 3 (merged): b_all = [fuse_b ; Wc@fuse_b + bc] AND W2 = Wc @ fuse_w
  k_b2g2<<<644, 256, 0, stream>>>(Wc_st, fuse_b, bc, b_all, fuse_wT, W_all + DD);

  // launch 4: main C = s @ W_all.T + b_all, scatter into d_out
  gemm_main<<<dim3(768), 512, 0, stream>>>(s_bf, W_all, out, b_all, 16384, 3072, 1024);
}

// Round 12
// 216.319 us; speedup vs baseline: 1.0046x; 1.0046x over previous
//
#include <hip/hip_runtime.h>
#include <stdint.h>

typedef float f32x4 __attribute__((ext_vector_type(4)));
typedef short s16x8 __attribute__((ext_vector_type(8)));
typedef short s16x4 __attribute__((ext_vector_type(4)));

__device__ __forceinline__ short f2bf(float f){
  union { float f; unsigned u; } v; v.f = f;
  unsigned r = v.u + 0x7FFFu + ((v.u >> 16) & 1u);
  return (short)(r >> 16);
}
__device__ __forceinline__ float bf2f(short h){
  union { unsigned u; float f; } v; v.u = ((unsigned)(unsigned short)h) << 16;
  return v.f;
}

// ---------- fused prep: addcvt (blocks 0..8191), cvt x3 (8192..11263),
// transcvt x3 (11264..14335), bias1 (14336..14847) ----------
__global__ void k_prep(const float* __restrict__ ta, const float* __restrict__ tb,
                       short* __restrict__ so,
                       const float* __restrict__ c0s, short* __restrict__ c0d,
                       const float* __restrict__ c1s, short* __restrict__ c1d,
                       const float* __restrict__ c2s, short* __restrict__ c2d,
                       const float* __restrict__ t0s, short* __restrict__ t0d,
                       const float* __restrict__ t1s, short* __restrict__ t1d,
                       const float* __restrict__ t2s, short* __restrict__ t2d,
                       const float* __restrict__ wt, const float* __restrict__ bvt, const float* __restrict__ obt,
                       const float* __restrict__ wi, const float* __restrict__ bvi, const float* __restrict__ obi,
                       float* __restrict__ bc){
  int bid = blockIdx.x;
  int tid = threadIdx.x;
  if (bid < 8192) {
    long i = (long)bid * 256 + tid;
    const f32x4* a4 = (const f32x4*)ta;
    const f32x4* b4 = (const f32x4*)tb;
    f32x4 x0 = a4[2*i], x1 = a4[2*i+1];
    f32x4 y0 = b4[2*i], y1 = b4[2*i+1];
    s16x8 r;
    #pragma unroll
    for (int j=0;j<4;j++){ r[j] = f2bf(x0[j]+y0[j]); r[j+4] = f2bf(x1[j]+y1[j]); }
    *(s16x8*)(so + i*8) = r;
    return;
  }
  bid -= 8192;
  if (bid < 3072) {
    int z = bid >> 10, b = bid & 1023;
    const float* in = (z==0) ? c0s : ((z==1) ? c1s : c2s);
    short* out      = (z==0) ? c0d : ((z==1) ? c1d : c2d);
    long i = (long)b*256 + tid;
    f32x4 v = ((const f32x4*)in)[i];
    s16x4 r;
    #pragma unroll
    for (int j=0;j<4;j++) r[j] = f2bf(v[j]);
    *(s16x4*)(out + i*4) = r;
  } else if (bid < 6144) {
    int q = bid - 3072;
    int z = q >> 10, b = q & 1023;
    const float* in = (z==0) ? t0s : ((z==1) ? t1s : t2s);
    short* out      = (z==0) ? t0d : ((z==1) ? t1d : t2d);
    __shared__ float tile[32][33];
    int tx = tid & 31, ty = tid >> 5;
    int c0 = (b & 31)*32, r0 = (b >> 5)*32;
    #pragma unroll
    for (int i=ty; i<32; i+=8)
      tile[i][tx] = in[(long)(r0+i)*1024 + c0 + tx];
    __syncthreads();
    #pragma unroll
    for (int i=ty; i<32; i+=8)
      out[(long)(c0+i)*1024 + r0 + tx] = f2bf(tile[tx][i]);
  } else {
    int q = bid - 6144;
    int z = q >> 8, b = q & 255;
    const float* w  = z ? wi  : wt;
    const float* bv = z ? bvi : bvt;
    const float* ob = z ? obi : obt;
    int n = b*4 + (tid>>6);
    int lane = tid & 63;
    const float* row = w + (long)n*1024;
    float acc = 0.f;
    for (int j=lane; j<1024; j+=64) acc += row[j]*bv[j];
    #pragma unroll
    for (int m=32;m;m>>=1) acc += __shfl_xor(acc, m, 64);
    if (lane==0) bc[z*1024+n] = acc + ob[n];
  }
}

#define GLDS(src, dst) __builtin_amdgcn_global_load_lds( \
    (const __attribute__((address_space(1))) void*)(src), \
    (__attribute__((address_space(3))) void*)(dst), 16, 0, 0)

// ---------- small NT GEMM body (128x128 tile, m97 structure): C bf16 = A@B^T ----------
__device__ __forceinline__
void gemm_small_body(const short* __restrict__ A, const short* __restrict__ B,
                     short* __restrict__ C, int N, int K, int m0, int n0,
                     short* ldsA, short* ldsB, int tid)
{
  const int lane = tid & 63;
  const int wv = tid >> 6;
  const int wm = wv >> 1, wn = wv & 1;

  f32x4 acc[4][4];
  #pragma unroll
  for (int i=0;i<4;i++)
    #pragma unroll
    for (int j=0;j<4;j++) acc[i][j] = (f32x4){0.f,0.f,0.f,0.f};

  const int bo0 = wv*1024 + lane*16;
  const int bo1 = bo0 + 4096;
  const int r0 = bo0 >> 6, c0 = bo0 & 63;
  const int r1 = bo1 >> 6, c1 = bo1 & 63;
  const long rsb = (long)K * 2;

  const char* Ab = (const char*)A;
  const char* Bb = (const char*)B;
  char* lA = (char*)ldsA;
  char* lB = (char*)ldsB;

  const int nkt = K >> 5;
  for (int kt = 0; kt < nkt; ++kt) {
    const long kb = (long)kt * 64;
    GLDS(Ab + (long)(m0 + r0)*rsb + kb + c0, lA + wv*1024);
    GLDS(Ab + (long)(m0 + r1)*rsb + kb + c1, lA + 4096 + wv*1024);
    GLDS(Bb + (long)(n0 + r0)*rsb + kb + c0, lB + wv*1024);
    GLDS(Bb + (long)(n0 + r1)*rsb + kb + c1, lB + 4096 + wv*1024);
    __syncthreads();

    s16x8 af[4], bfv[4];
    #pragma unroll
    for (int i=0;i<4;i++)
      af[i] = *(const s16x8*)(lA + (wm*64 + i*16 + (lane&15))*64 + (lane>>4)*16);
    #pragma unroll
    for (int j=0;j<4;j++)
      bfv[j] = *(const s16x8*)(lB + (wn*64 + j*16 + (lane&15))*64 + (lane>>4)*16);

    #pragma unroll
    for (int i=0;i<4;i++)
      #pragma unroll
      for (int j=0;j<4;j++)
        acc[i][j] = __builtin_amdgcn_mfma_f32_16x16x32_bf16(af[i], bfv[j], acc[i][j], 0, 0, 0);
    __syncthreads();
  }

  #pragma unroll
  for (int j=0;j<4;j++){
    int gn = n0 + wn*64 + j*16 + (lane&15);
    #pragma unroll
    for (int i=0;i<4;i++){
      int gmb = m0 + wm*64 + i*16 + ((lane>>4)*4);
      #pragma unroll
      for (int r=0;r<4;r++)
        C[(long)(gmb+r)*N + gn] = f2bf(acc[i][j][r]);
    }
  }
}

// launch 2: Wc_z = out_w_z @ wv_z (z batches via blockIdx.z)
__global__ __launch_bounds__(256, 2)
void gemm_wc(const short* __restrict__ Abase, const short* __restrict__ Bbase,
             short* __restrict__ Cbase, long zA, long zB, long zC)
{
  __shared__ __align__(16) short ldsA[128*32];
  __shared__ __align__(16) short ldsB[128*32];
  gemm_small_body(Abase + (long)blockIdx.z*zA, Bbase + (long)blockIdx.z*zB,
                  Cbase + (long)blockIdx.z*zC, 1024, 1024,
                  blockIdx.x*128, blockIdx.y*128, ldsA, ldsB, threadIdx.x);
}

// launch 3 (merged): blocks 0..515 = bias2+copy; 516..643 = W2 = Wc @ fuse_w
__global__ __launch_bounds__(256, 2)
void k_b2g2(const short* __restrict__ Wc, const float* __restrict__ fuse_b,
            const float* __restrict__ bc, float* __restrict__ b_all,
            const short* __restrict__ fuse_wT, short* __restrict__ W2)
{
  __shared__ __align__(16) short ldsA[128*32];
  __shared__ __align__(16) short ldsB[128*32];
  int bid = blockIdx.x;
  if (bid < 512) {
    int n = bid*4 + (threadIdx.x>>6);
    int lane = threadIdx.x & 63;
    const short* row = Wc + (long)n*1024;
    float acc = 0.f;
    for (int j=lane; j<1024; j+=64) acc += bf2f(row[j])*fuse_b[j];
    #pragma unroll
    for (int m=32;m;m>>=1) acc += __shfl_xor(acc, m, 64);
    if (lane==0) b_all[1024+n] = acc + bc[n];
    return;
  }
  if (bid < 516) {
    int i = (bid - 512)*256 + threadIdx.x;
    b_all[i] = fuse_b[i];
    return;
  }
  int g = bid - 516;                 // 0..127 -> 16 x 8 tiles of 2048x1024
  gemm_small_body(Wc, fuse_wT, W2, 1024, 1024,
                  (g & 15)*128, (g >> 4)*128, ldsA, ldsB, threadIdx.x);
}

// ---------- main NT GEMM: 256x256, BK=64, PERSISTENT grid (R12) ----------
// 256 blocks x 3 tiles (wg, wg+256, wg+512 — same XCD: 256%8==0). K-loop flat:
// 48 steps (tile = g>>4, kt = g&15). Schedule body = R11 verified trace:
//   ks0(g): read bfr=B(g) x8 + af=A(g,ks0) x8; barA; LGKM0; 32 MFMA.
//   ks1(g): read af=A(g,ks1) x8; VMW0 [drains step g+1 operands, issued @g-1];
//           barB; LGKM0; barC [all waves' reads done]; stage step g+2 (A+B,
//           8 GLDS) — crosses tile boundaries, prefetching the next tile;
//           32 MFMA. At kt==15: epilogue for tile g>>4, acc reset — stores
//           overlap next tile's staged loads + first MFMAs.
// Read-safety: step s operands issued @(s-2,ks1), drained @(s-1,ks1) VMW0,
// fenced by its barriers, first read @(s,ks0) — 2-phase slack (R11 invariant).
// Write-safety: stage targets' last reads complete before barC (every wave's
// LGKM0 precedes it). Epilogue stores make the next VMW0 conservative (waits
// for store L2-commit too) — correct, ~2K cyc cost at 2 boundaries.
#define MFMA16 __builtin_amdgcn_mfma_f32_16x16x32_bf16
#define VMW0 asm volatile("s_waitcnt vmcnt(0)" ::: "memory")
#define LGKM0 asm volatile("s_waitcnt lgkmcnt(0)" ::: "memory")
#define MEMF asm volatile("" ::: "memory")

__global__ __launch_bounds__(512, 2)
void gemm_main(const short* __restrict__ A, const short* __restrict__ B,
               float* __restrict__ O, const float* __restrict__ bias,
               int M, int N, int K)
{
  __shared__ __align__(16) char lds[131072];

  const int nbn = N >> 8;                  // 12
  const int nwg = (M >> 8) * nbn;          // 768
  const int cpx = nwg >> 3;                // 96
  // three tiles for this block (branchless uniform selects; no runtime arrays)
  int m0s0, n0s0, m0s1, n0s1, m0s2, n0s2;
  {
    int wg = blockIdx.x;
    int sz = (wg & 7) * cpx + (wg >> 3); m0s0 = (sz / nbn) << 8; n0s0 = (sz % nbn) << 8;
    wg = blockIdx.x + 256;
    sz = (wg & 7) * cpx + (wg >> 3);     m0s1 = (sz / nbn) << 8; n0s1 = (sz % nbn) << 8;
    wg = blockIdx.x + 512;
    sz = (wg & 7) * cpx + (wg >> 3);     m0s2 = (sz / nbn) << 8; n0s2 = (sz % nbn) << 8;
  }

  const int tid  = threadIdx.x;
  const int lane = tid & 63;
  const int wid  = tid >> 6;
  const int wm   = wid >> 2;   // 0..1
  const int wn   = wid & 3;    // 0..3
  const long rsb = (long)K * 2;
  const char* Ab = (const char*)A;
  const char* Bb = (const char*)B;

  f32x4 acc[8][4];
  #pragma unroll
  for (int i=0;i<8;i++)
    #pragma unroll
    for (int j=0;j<4;j++) acc[i][j] = (f32x4){0.f,0.f,0.f,0.f};

  // Stage source precompute: linear LDS dest chunk c receives logical chunk
  // q = c ^ ((c>>3)&7)  (row preserved; inverse of the read swizzle).
  int srow[2][2]; int scol[2][2]; int sdst[2][2];
  #pragma unroll
  for (int H=0;H<2;H++)
    #pragma unroll
    for (int sb=0;sb<2;sb++){
      int c = H*1024 + sb*512 + wid*64 + lane;
      int q = c ^ ((c>>3)&7);
      srow[H][sb] = q >> 3;
      scol[H][sb] = (q & 7) << 4;
      sdst[H][sb] = (H*1024 + sb*512 + wid*64) << 4;
    }

  auto stage = [&](const char* P, int tr0, int kt, int RB, int H){
    const long ktb = (long)kt << 7;
    GLDS(P + ((long)(tr0 + srow[H][0]))*rsb + ktb + scol[H][0], lds + RB + sdst[H][0]);
    GLDS(P + ((long)(tr0 + srow[H][1]))*rsb + ktb + scol[H][1], lds + RB + sdst[H][1]);
  };

  const int swx = (lane & 7) << 4;   // read swizzle (row&7 == lane&7 for all frags)
  auto ldA = [&](int RB, int i, int ks) -> s16x8 {
    int off = (wm*128 + i*16 + (lane&15))*128 + ks*64 + ((lane>>4)<<4);
    off ^= swx;
    return *(const s16x8*)(lds + RB + off);
  };
  auto ldB = [&](int RB, int j, int ks) -> s16x8 {
    int off = (wn*64 + j*16 + (lane&15))*128 + ks*64 + ((lane>>4)<<4);
    off ^= swx;
    return *(const s16x8*)(lds + 65536 + RB + off);
  };

  s16x8 bfr[4][2];
  s16x8 af[8];
  const int nst = (K >> 6) * 3;      // 48 flat steps

  // Prologue (once): stage steps 0 and 1 (both tile 0); full drain.
  stage(Ab, m0s0, 0, 0,     0); stage(Ab, m0s0, 0, 0,     1);
  stage(Bb, n0s0, 0, 65536, 0); stage(Bb, n0s0, 0, 65536, 1);
  stage(Ab, m0s0, 1, 32768, 0); stage(Ab, m0s0, 1, 32768, 1);
  stage(Bb, n0s0, 1, 98304, 0); stage(Bb, n0s0, 1, 98304, 1);
  VMW0; MEMF;
  __builtin_amdgcn_s_barrier();

  for (int g = 0; g < nst; ++g) {
    const int RB = (g & 1) << 15;
    // -------- ks0 phase (no staging) --------
    #pragma unroll
    for (int j=0;j<4;j++){ bfr[j][0] = ldB(RB, j, 0); bfr[j][1] = ldB(RB, j, 1); }
    #pragma unroll
    for (int i=0;i<8;i++) af[i] = ldA(RB, i, 0);
    MEMF;
    __builtin_amdgcn_s_barrier();          // bar A
    LGKM0;
    __builtin_amdgcn_s_setprio(1);
    #pragma unroll
    for (int i=0;i<8;i++)
      #pragma unroll
      for (int j=0;j<4;j++)
        acc[i][j] = MFMA16(af[i], bfr[j][0], acc[i][j], 0, 0, 0);
    __builtin_amdgcn_s_setprio(0);
    // -------- ks1 phase (all staging, 2-phase slack) --------
    #pragma unroll
    for (int i=0;i<8;i++) af[i] = ldA(RB, i, 1);
    VMW0; MEMF;                            // drains step g+1 operands (issued @g-1)
    __builtin_amdgcn_s_barrier();          // bar B
    LGKM0;                                 // own LDS reads complete
    MEMF;
    __builtin_amdgcn_s_barrier();          // bar C: ALL waves' reads complete
    {
      const int s = g + 2;
      if (s < nst) {
        int ti = s >> 4;
        int sm0 = (ti==0) ? m0s0 : ((ti==1) ? m0s1 : m0s2);
        int sn0 = (ti==0) ? n0s0 : ((ti==1) ? n0s1 : n0s2);
        int skt = s & 15;
        stage(Ab, sm0, skt, RB, 0);          stage(Ab, sm0, skt, RB, 1);
        stage(Bb, sn0, skt, 65536 + RB, 0);  stage(Bb, sn0, skt, 65536 + RB, 1);
      }
    }
    __builtin_amdgcn_s_setprio(1);
    #pragma unroll
    for (int i=0;i<8;i++)
      #pragma unroll
      for (int j=0;j<4;j++)
        acc[i][j] = MFMA16(af[i], bfr[j][1], acc[i][j], 0, 0, 0);
    __builtin_amdgcn_s_setprio(0);

    // -------- per-tile epilogue (uniform branch), overlaps next tile's loads ----
    if ((g & 15) == 15) {
      int ti = g >> 4;
      int em0 = (ti==0) ? m0s0 : ((ti==1) ? m0s1 : m0s2);
      int en0 = (ti==0) ? n0s0 : ((ti==1) ? n0s1 : n0s2);
      const long BD = (long)M * 1024L;
      #pragma unroll
      for (int j=0;j<4;j++){
        int gn = en0 + wn*64 + j*16 + (lane&15);
        float bb = bias[gn];
        int region = gn >> 10;
        long rbase = (region==0) ? 2*BD : ((region==1) ? 0L : BD);
        int col = gn & 1023;
        #pragma unroll
        for (int i=0;i<8;i++){
          int gr = em0 + wm*128 + i*16 + ((lane>>4)<<2);
          #pragma unroll
          for (int r=0;r<4;r++)
            O[rbase + (long)(gr+r)*1024 + col] = acc[i][j][r] + bb;
        }
      }
      #pragma unroll
      for (int i=0;i<8;i++)
        #pragma unroll
        for (int j=0;j<4;j++) acc[i][j] = (f32x4){0.f,0.f,0.f,0.f};
    }
  }
}

extern "C" void kernel_launch(void* const* d_in, const int* in_sizes, int n_in,
                              void* d_out, int out_size, void* d_ws, size_t ws_size,
                              hipStream_t stream) {
  const float* text    = (const float*)d_in[0];
  const float* image   = (const float*)d_in[1];
  const float* fuse_w  = (const float*)d_in[2];
  const float* fuse_b  = (const float*)d_in[3];
  const float* t_in_w  = (const float*)d_in[4];
  const float* t_in_b  = (const float*)d_in[5];
  const float* t_out_w = (const float*)d_in[6];
  const float* t_out_b = (const float*)d_in[7];
  const float* i_in_w  = (const float*)d_in[8];
  const float* i_in_b  = (const float*)d_in[9];
  const float* i_out_w = (const float*)d_in[10];
  const float* i_out_b = (const float*)d_in[11];
  float* out = (float*)d_out;

  const long DD = 1024L*1024L;
  char* ws = (char*)d_ws;
  short* s_bf    = (short*)ws; ws += 16384L*1024*2;
  short* W_all   = (short*)ws; ws += 3*DD*2;      // rows: [fuse_w; Wt2; Wi2]
  short* wvT     = (short*)ws; ws += 2*DD*2;      // [wvT_t; wvT_i]
  short* fuse_wT = (short*)ws; ws += DD*2;
  short* outw_st = (short*)ws; ws += 2*DD*2;      // [t_out_w; i_out_w] bf16
  short* Wc_st   = (short*)ws; ws += 2*DD*2;      // [Wc_t; Wc_i]
  float* bc      = (float*)ws; ws += 2048*4;
  float* b_all   = (float*)ws; ws += 3072*4;

  // launch 1: all elementwise prep (addcvt + cvt + transcvt + bias1)
  k_prep<<<14848, 256, 0, stream>>>(text, image, s_bf,
                                    fuse_w, W_all,
                                    t_out_w, outw_st,
                                    i_out_w, outw_st + DD,
                                    t_in_w + 2*DD, wvT,
                                    i_in_w + 2*DD, wvT + DD,
                                    fuse_w, fuse_wT,
                                    t_out_w, t_in_b + 2048, t_out_b,
                                    i_out_w, i_in_b + 2048, i_out_b, bc);

  // launch 2: Wc_z = out_w_z @ wv_z
  gemm_wc<<<dim3(8,8,2), 256, 0, stream>>>(outw_st, wvT, Wc_st, DD, DD, DD);

  // launch 3 (merged): b_all = [fuse_b ; Wc@fuse_b + bc] AND W2 = Wc @ fuse_w
  k_b2g2<<<644, 256, 0, stream>>>(Wc_st, fuse_b, bc, b_all, fuse_wT, W_all + DD);

  // launch 4: main C = s @ W_all.T + b_all (persistent: 256 blocks x 3 tiles)
  gemm_main<<<dim3(256), 512, 0, stream>>>(s_bf, W_all, out, b_all, 16384, 3072, 1024);
}

// Round 13
// 209.486 us; speedup vs baseline: 1.0374x; 1.0326x over previous
//
#include <hip/hip_runtime.h>
#include <stdint.h>

typedef float f32x4 __attribute__((ext_vector_type(4)));
typedef short s16x8 __attribute__((ext_vector_type(8)));
typedef short s16x4 __attribute__((ext_vector_type(4)));

__device__ __forceinline__ short f2bf(float f){
  union { float f; unsigned u; } v; v.f = f;
  unsigned r = v.u + 0x7FFFu + ((v.u >> 16) & 1u);
  return (short)(r >> 16);
}
__device__ __forceinline__ float bf2f(short h){
  union { unsigned u; float f; } v; v.u = ((unsigned)(unsigned short)h) << 16;
  return v.f;
}

// ---------- fused prep: addcvt (blocks 0..8191), cvt x3 (8192..11263),
// transcvt x3 (11264..14335), bias1 (14336..14847) ----------
__global__ void k_prep(const float* __restrict__ ta, const float* __restrict__ tb,
                       short* __restrict__ so,
                       const float* __restrict__ c0s, short* __restrict__ c0d,
                       const float* __restrict__ c1s, short* __restrict__ c1d,
                       const float* __restrict__ c2s, short* __restrict__ c2d,
                       const float* __restrict__ t0s, short* __restrict__ t0d,
                       const float* __restrict__ t1s, short* __restrict__ t1d,
                       const float* __restrict__ t2s, short* __restrict__ t2d,
                       const float* __restrict__ wt, const float* __restrict__ bvt, const float* __restrict__ obt,
                       const float* __restrict__ wi, const float* __restrict__ bvi, const float* __restrict__ obi,
                       float* __restrict__ bc){
  int bid = blockIdx.x;
  int tid = threadIdx.x;
  if (bid < 8192) {
    long i = (long)bid * 256 + tid;
    const f32x4* a4 = (const f32x4*)ta;
    const f32x4* b4 = (const f32x4*)tb;
    f32x4 x0 = a4[2*i], x1 = a4[2*i+1];
    f32x4 y0 = b4[2*i], y1 = b4[2*i+1];
    s16x8 r;
    #pragma unroll
    for (int j=0;j<4;j++){ r[j] = f2bf(x0[j]+y0[j]); r[j+4] = f2bf(x1[j]+y1[j]); }
    *(s16x8*)(so + i*8) = r;
    return;
  }
  bid -= 8192;
  if (bid < 3072) {
    int z = bid >> 10, b = bid & 1023;
    const float* in = (z==0) ? c0s : ((z==1) ? c1s : c2s);
    short* out      = (z==0) ? c0d : ((z==1) ? c1d : c2d);
    long i = (long)b*256 + tid;
    f32x4 v = ((const f32x4*)in)[i];
    s16x4 r;
    #pragma unroll
    for (int j=0;j<4;j++) r[j] = f2bf(v[j]);
    *(s16x4*)(out + i*4) = r;
  } else if (bid < 6144) {
    int q = bid - 3072;
    int z = q >> 10, b = q & 1023;
    const float* in = (z==0) ? t0s : ((z==1) ? t1s : t2s);
    short* out      = (z==0) ? t0d : ((z==1) ? t1d : t2d);
    __shared__ float tile[32][33];
    int tx = tid & 31, ty = tid >> 5;
    int c0 = (b & 31)*32, r0 = (b >> 5)*32;
    #pragma unroll
    for (int i=ty; i<32; i+=8)
      tile[i][tx] = in[(long)(r0+i)*1024 + c0 + tx];
    __syncthreads();
    #pragma unroll
    for (int i=ty; i<32; i+=8)
      out[(long)(c0+i)*1024 + r0 + tx] = f2bf(tile[tx][i]);
  } else {
    int q = bid - 6144;
    int z = q >> 8, b = q & 255;
    const float* w  = z ? wi  : wt;
    const float* bv = z ? bvi : bvt;
    const float* ob = z ? obi : obt;
    int n = b*4 + (tid>>6);
    int lane = tid & 63;
    const float* row = w + (long)n*1024;
    float acc = 0.f;
    for (int j=lane; j<1024; j+=64) acc += row[j]*bv[j];
    #pragma unroll
    for (int m=32;m;m>>=1) acc += __shfl_xor(acc, m, 64);
    if (lane==0) bc[z*1024+n] = acc + ob[n];
  }
}

#define GLDS(src, dst) __builtin_amdgcn_global_load_lds( \
    (const __attribute__((address_space(1))) void*)(src), \
    (__attribute__((address_space(3))) void*)(dst), 16, 0, 0)

// ---------- small NT GEMM body (128x128 tile, m97 structure): C bf16 = A@B^T ----------
__device__ __forceinline__
void gemm_small_body(const short* __restrict__ A, const short* __restrict__ B,
                     short* __restrict__ C, int N, int K, int m0, int n0,
                     short* ldsA, short* ldsB, int tid)
{
  const int lane = tid & 63;
  const int wv = tid >> 6;
  const int wm = wv >> 1, wn = wv & 1;

  f32x4 acc[4][4];
  #pragma unroll
  for (int i=0;i<4;i++)
    #pragma unroll
    for (int j=0;j<4;j++) acc[i][j] = (f32x4){0.f,0.f,0.f,0.f};

  const int bo0 = wv*1024 + lane*16;
  const int bo1 = bo0 + 4096;
  const int r0 = bo0 >> 6, c0 = bo0 & 63;
  const int r1 = bo1 >> 6, c1 = bo1 & 63;
  const long rsb = (long)K * 2;

  const char* Ab = (const char*)A;
  const char* Bb = (const char*)B;
  char* lA = (char*)ldsA;
  char* lB = (char*)ldsB;

  const int nkt = K >> 5;
  for (int kt = 0; kt < nkt; ++kt) {
    const long kb = (long)kt * 64;
    GLDS(Ab + (long)(m0 + r0)*rsb + kb + c0, lA + wv*1024);
    GLDS(Ab + (long)(m0 + r1)*rsb + kb + c1, lA + 4096 + wv*1024);
    GLDS(Bb + (long)(n0 + r0)*rsb + kb + c0, lB + wv*1024);
    GLDS(Bb + (long)(n0 + r1)*rsb + kb + c1, lB + 4096 + wv*1024);
    __syncthreads();

    s16x8 af[4], bfv[4];
    #pragma unroll
    for (int i=0;i<4;i++)
      af[i] = *(const s16x8*)(lA + (wm*64 + i*16 + (lane&15))*64 + (lane>>4)*16);
    #pragma unroll
    for (int j=0;j<4;j++)
      bfv[j] = *(const s16x8*)(lB + (wn*64 + j*16 + (lane&15))*64 + (lane>>4)*16);

    #pragma unroll
    for (int i=0;i<4;i++)
      #pragma unroll
      for (int j=0;j<4;j++)
        acc[i][j] = __builtin_amdgcn_mfma_f32_16x16x32_bf16(af[i], bfv[j], acc[i][j], 0, 0, 0);
    __syncthreads();
  }

  #pragma unroll
  for (int j=0;j<4;j++){
    int gn = n0 + wn*64 + j*16 + (lane&15);
    #pragma unroll
    for (int i=0;i<4;i++){
      int gmb = m0 + wm*64 + i*16 + ((lane>>4)*4);
      #pragma unroll
      for (int r=0;r<4;r++)
        C[(long)(gmb+r)*N + gn] = f2bf(acc[i][j][r]);
    }
  }
}

// launch 2: Wc_z = out_w_z @ wv_z (z batches via blockIdx.z)
__global__ __launch_bounds__(256, 2)
void gemm_wc(const short* __restrict__ Abase, const short* __restrict__ Bbase,
             short* __restrict__ Cbase, long zA, long zB, long zC)
{
  __shared__ __align__(16) short ldsA[128*32];
  __shared__ __align__(16) short ldsB[128*32];
  gemm_small_body(Abase + (long)blockIdx.z*zA, Bbase + (long)blockIdx.z*zB,
                  Cbase + (long)blockIdx.z*zC, 1024, 1024,
                  blockIdx.x*128, blockIdx.y*128, ldsA, ldsB, threadIdx.x);
}

// launch 3 (merged): blocks 0..515 = bias2+copy; 516..643 = W2 = Wc @ fuse_w
__global__ __launch_bounds__(256, 2)
void k_b2g2(const short* __restrict__ Wc, const float* __restrict__ fuse_b,
            const float* __restrict__ bc, float* __restrict__ b_all,
            const short* __restrict__ fuse_wT, short* __restrict__ W2)
{
  __shared__ __align__(16) short ldsA[128*32];
  __shared__ __align__(16) short ldsB[128*32];
  int bid = blockIdx.x;
  if (bid < 512) {
    int n = bid*4 + (threadIdx.x>>6);
    int lane = threadIdx.x & 63;
    const short* row = Wc + (long)n*1024;
    float acc = 0.f;
    for (int j=lane; j<1024; j+=64) acc += bf2f(row[j])*fuse_b[j];
    #pragma unroll
    for (int m=32;m;m>>=1) acc += __shfl_xor(acc, m, 64);
    if (lane==0) b_all[1024+n] = acc + bc[n];
    return;
  }
  if (bid < 516) {
    int i = (bid - 512)*256 + threadIdx.x;
    b_all[i] = fuse_b[i];
    return;
  }
  int g = bid - 516;                 // 0..127 -> 16 x 8 tiles of 2048x1024
  gemm_small_body(Wc, fuse_wT, W2, 1024, 1024,
                  (g & 15)*128, (g >> 4)*128, ldsA, ldsB, threadIdx.x);
}

// ---------- main NT GEMM: 256x256, BK=64, R7 schedule + ZERO-VALU addressing ----------
// R13 change: all ds_read addresses precomputed as base-VGPR + compile-time
// immediate. Derivation: swizzle XOR (bits 4-6) and ks*64|(lane>>4)<<4 (bits
// 4-6) never carry, so off = base(lane,w) + RB + i*2048 + laneoff(ks) with
// laneoff(ks=1) = laneoff(0)^64 — per-lane constants. Full 16x K-unroll makes
// RB compile-time. Stage sources are 8 running 64-bit pointers (+=128/K-tile).
// Sync skeleton byte-for-byte = R7's verified trace:
//   ks0(t): read bfr(B,t) x8 + af(A,t,ks0) x8; VMW4; bar; stage A(t+1); LGKM0;
//           32 MFMA.
//   ks1(t): read af(A,t,ks1) x8; VMW0; bar; stage B(t+2); LGKM0; 32 MFMA.
// Queue trace (4-load units): entry ks0(t): [B(t+1)]; VMW4 no-op; +A(t+1);
// ks1(t): VMW0 drains B(t+1)+A(t+1); +B(t+2). All reads of a tile are fenced
// one full phase after its drain. Write-targets' last reads complete before
// each wave's pre-MFMA LGKM0 one phase before the overwriting stage (R6 audit).
#define MFMA16 __builtin_amdgcn_mfma_f32_16x16x32_bf16
#define VMW4 asm volatile("s_waitcnt vmcnt(4)" ::: "memory")
#define VMW0 asm volatile("s_waitcnt vmcnt(0)" ::: "memory")
#define LGKM0 asm volatile("s_waitcnt lgkmcnt(0)" ::: "memory")
#define MEMF asm volatile("" ::: "memory")

__global__ __launch_bounds__(512, 2)
void gemm_main(const short* __restrict__ A, const short* __restrict__ B,
               float* __restrict__ O, const float* __restrict__ bias,
               int M, int N)
{
  __shared__ __align__(16) char lds[131072];
  constexpr int K = 1024;
  constexpr int nkt = 16;

  const int nbn = N >> 8;
  const int nwg = (M >> 8) * nbn;
  const int cpx = nwg >> 3;
  int bid = blockIdx.x;
  int swz = (bid & 7) * cpx + (bid >> 3);
  const int m0 = (swz / nbn) << 8;
  const int n0 = (swz % nbn) << 8;

  const int tid  = threadIdx.x;
  const int lane = tid & 63;
  const int wid  = tid >> 6;
  const int wm   = wid >> 2;   // 0..1
  const int wn   = wid & 3;    // 0..3
  const long rsb = (long)K * 2;

  f32x4 acc[8][4];
  #pragma unroll
  for (int i=0;i<8;i++)
    #pragma unroll
    for (int j=0;j<4;j++) acc[i][j] = (f32x4){0.f,0.f,0.f,0.f};

  // ---- precomputed LDS read bases (zero per-read VALU) ----
  const int lo0 = (((lane>>4)<<4)) ^ ((lane&7)<<4);
  const int lo1 = lo0 ^ 64;
  const char* pA0 = lds + wm*16384 + (lane&15)*128 + lo0;          // A, ks=0
  const char* pA1 = lds + wm*16384 + (lane&15)*128 + lo1;          // A, ks=1
  const char* pB0 = lds + 65536 + wn*8192 + (lane&15)*128 + lo0;   // B, ks=0
  const char* pB1 = lds + 65536 + wn*8192 + (lane&15)*128 + lo1;   // B, ks=1

  // ---- stage destinations (wave-uniform) + running source pointers ----
  int sdst[2][2];
  const char* Apt[2][2];
  const char* Bpt[2][2];
  #pragma unroll
  for (int H=0;H<2;H++)
    #pragma unroll
    for (int sb=0;sb<2;sb++){
      int c = H*1024 + sb*512 + wid*64 + lane;
      int q = c ^ ((c>>3)&7);
      sdst[H][sb] = (H*1024 + sb*512 + wid*64) << 4;
      const long roff = (long)(q >> 3) * rsb + ((q & 7) << 4);
      Apt[H][sb] = (const char*)A + (long)m0*rsb + roff + 128;  // first use kt=1
      Bpt[H][sb] = (const char*)B + (long)n0*rsb + roff + 256;  // first use kt=2
    }

  // Prologue: A(0)->Abuf0, B(0)->Bbuf0, B(1)->Bbuf1 (12 loads); VMW4 leaves
  // B(1)x4 in flight (drained at ks1(0) VMW0).
  #pragma unroll
  for (int H=0;H<2;H++)
    #pragma unroll
    for (int sb=0;sb<2;sb++)
      GLDS(Apt[H][sb] - 128, lds + sdst[H][sb]);
  #pragma unroll
  for (int H=0;H<2;H++)
    #pragma unroll
    for (int sb=0;sb<2;sb++)
      GLDS(Bpt[H][sb] - 256, lds + 65536 + sdst[H][sb]);
  #pragma unroll
  for (int H=0;H<2;H++)
    #pragma unroll
    for (int sb=0;sb<2;sb++)
      GLDS(Bpt[H][sb] - 128, lds + 98304 + sdst[H][sb]);
  VMW4; MEMF;
  __builtin_amdgcn_s_barrier();

  s16x8 bfr[4][2];
  s16x8 af[8];

  #pragma unroll
  for (int t = 0; t < nkt; ++t) {
    const int RB = (t & 1) << 15;               // compile-time per iteration
    // -------- ks0 phase --------
    #pragma unroll
    for (int j=0;j<4;j++){
      bfr[j][0] = *(const s16x8*)(pB0 + RB + j*2048);
      bfr[j][1] = *(const s16x8*)(pB1 + RB + j*2048);
    }
    #pragma unroll
    for (int i=0;i<8;i++) af[i] = *(const s16x8*)(pA0 + RB + i*2048);
    VMW4; MEMF;
    __builtin_amdgcn_s_barrier();
    if (t+1 < nkt) {
      const int AB2 = ((t+1)&1) << 15;          // compile-time
      #pragma unroll
      for (int H=0;H<2;H++)
        #pragma unroll
        for (int sb=0;sb<2;sb++){
          GLDS(Apt[H][sb], lds + AB2 + sdst[H][sb]);
          Apt[H][sb] += 128;
        }
    }
    LGKM0;
    __builtin_amdgcn_s_setprio(1);
    #pragma unroll
    for (int i=0;i<8;i++)
      #pragma unroll
      for (int j=0;j<4;j++)
        acc[i][j] = MFMA16(af[i], bfr[j][0], acc[i][j], 0, 0, 0);
    __builtin_amdgcn_s_setprio(0);
    // -------- ks1 phase --------
    #pragma unroll
    for (int i=0;i<8;i++) af[i] = *(const s16x8*)(pA1 + RB + i*2048);
    VMW0; MEMF;            // drains B(t+1) AND A(t+1) before the barrier
    __builtin_amdgcn_s_barrier();
    if (t+2 < nkt) {
      const int BB2 = 65536 + RB;               // compile-time
      #pragma unroll
      for (int H=0;H<2;H++)
        #pragma unroll
        for (int sb=0;sb<2;sb++){
          GLDS(Bpt[H][sb], lds + BB2 + sdst[H][sb]);
          Bpt[H][sb] += 128;
        }
    }
    LGKM0;
    __builtin_amdgcn_s_setprio(1);
    #pragma unroll
    for (int i=0;i<8;i++)
      #pragma unroll
      for (int j=0;j<4;j++)
        acc[i][j] = MFMA16(af[i], bfr[j][1], acc[i][j], 0, 0, 0);
    __builtin_amdgcn_s_setprio(0);
  }

  // Epilogue: fp32 + bias, scatter by output region (text | image | fused).
  const long BD = (long)M * 1024L;
  #pragma unroll
  for (int j=0;j<4;j++){
    int gn = n0 + wn*64 + j*16 + (lane&15);
    float bb = bias[gn];
    int region = gn >> 10;
    long rbase = (region==0) ? 2*BD : ((region==1) ? 0L : BD);
    int col = gn & 1023;
    #pragma unroll
    for (int i=0;i<8;i++){
      int gr = m0 + wm*128 + i*16 + ((lane>>4)<<2);
      #pragma unroll
      for (int r=0;r<4;r++)
        O[rbase + (long)(gr+r)*1024 + col] = acc[i][j][r] + bb;
    }
  }
}

extern "C" void kernel_launch(void* const* d_in, const int* in_sizes, int n_in,
                              void* d_out, int out_size, void* d_ws, size_t ws_size,
                              hipStream_t stream) {
  const float* text    = (const float*)d_in[0];
  const float* image   = (const float*)d_in[1];
  const float* fuse_w  = (const float*)d_in[2];
  const float* fuse_b  = (const float*)d_in[3];
  const float* t_in_w  = (const float*)d_in[4];
  const float* t_in_b  = (const float*)d_in[5];
  const float* t_out_w = (const float*)d_in[6];
  const float* t_out_b = (const float*)d_in[7];
  const float* i_in_w  = (const float*)d_in[8];
  const float* i_in_b  = (const float*)d_in[9];
  const float* i_out_w = (const float*)d_in[10];
  const float* i_out_b = (const float*)d_in[11];
  float* out = (float*)d_out;

  const long DD = 1024L*1024L;
  char* ws = (char*)d_ws;
  short* s_bf    = (short*)ws; ws += 16384L*1024*2;
  short* W_all   = (short*)ws; ws += 3*DD*2;      // rows: [fuse_w; Wt2; Wi2]
  short* wvT     = (short*)ws; ws += 2*DD*2;      // [wvT_t; wvT_i]
  short* fuse_wT = (short*)ws; ws += DD*2;
  short* outw_st = (short*)ws; ws += 2*DD*2;      // [t_out_w; i_out_w] bf16
  short* Wc_st   = (short*)ws; ws += 2*DD*2;      // [Wc_t; Wc_i]
  float* bc      = (float*)ws; ws += 2048*4;
  float* b_all   = (float*)ws; ws += 3072*4;

  // launch 1: all elementwise prep (addcvt + cvt + transcvt + bias1)
  k_prep<<<14848, 256, 0, stream>>>(text, image, s_bf,
                                    fuse_w, W_all,
                                    t_out_w, outw_st,
                                    i_out_w, outw_st + DD,
                                    t_in_w + 2*DD, wvT,
                                    i_in_w + 2*DD, wvT + DD,
                                    fuse_w, fuse_wT,
                                    t_out_w, t_in_b + 2048, t_out_b,
                                    i_out_w, i_in_b + 2048, i_out_b, bc);

  // launch 2: Wc_z = out_w_z @ wv_z
  gemm_wc<<<dim3(8,8,2), 256, 0, stream>>>(outw_st, wvT, Wc_st, DD, DD, DD);

  // launch 3 (merged): b_all = [fuse_b ; Wc@fuse_b + bc] AND W2 = Wc @ fuse_w
  k_b2g2<<<644, 256, 0, stream>>>(Wc_st, fuse_b, bc, b_all, fuse_wT, W_all + DD);

  // launch 4: main C = s @ W_all.T + b_all, scatter into d_out
  gemm_main<<<dim3(768), 512, 0, stream>>>(s_bf, W_all, out, b_all, 16384, 3072);
}

// Round 14
// 195.720 us; speedup vs baseline: 1.1104x; 1.0703x over previous
//
#include <hip/hip_runtime.h>
#include <stdint.h>

typedef float f32x4 __attribute__((ext_vector_type(4)));
typedef short s16x8 __attribute__((ext_vector_type(8)));
typedef short s16x4 __attribute__((ext_vector_type(4)));

__device__ __forceinline__ short f2bf(float f){
  union { float f; unsigned u; } v; v.f = f;
  unsigned r = v.u + 0x7FFFu + ((v.u >> 16) & 1u);
  return (short)(r >> 16);
}
__device__ __forceinline__ float bf2f(short h){
  union { unsigned u; float f; } v; v.u = ((unsigned)(unsigned short)h) << 16;
  return v.f;
}

// ---------- addcvt block: s_bf[gbid] = bf16(text+image), gbid in [0,8192) ----------
__device__ __forceinline__
void addcvt_block(int gbid, int tid, const float* __restrict__ ta,
                  const float* __restrict__ tb, short* __restrict__ so){
  long i = (long)gbid * 256 + tid;
  const f32x4* a4 = (const f32x4*)ta;
  const f32x4* b4 = (const f32x4*)tb;
  f32x4 x0 = a4[2*i], x1 = a4[2*i+1];
  f32x4 y0 = b4[2*i], y1 = b4[2*i+1];
  s16x8 r;
  #pragma unroll
  for (int j=0;j<4;j++){ r[j] = f2bf(x0[j]+y0[j]); r[j+4] = f2bf(x1[j]+y1[j]); }
  *(s16x8*)(so + i*8) = r;
}

// ---------- L1: weight prep (blocks 0..6655) + addcvt chunk (6656..9255) ----------
__global__ void k_prep1(const float* __restrict__ ta, const float* __restrict__ tb,
                        short* __restrict__ so,
                        const float* __restrict__ c0s, short* __restrict__ c0d,
                        const float* __restrict__ c1s, short* __restrict__ c1d,
                        const float* __restrict__ c2s, short* __restrict__ c2d,
                        const float* __restrict__ t0s, short* __restrict__ t0d,
                        const float* __restrict__ t1s, short* __restrict__ t1d,
                        const float* __restrict__ t2s, short* __restrict__ t2d,
                        const float* __restrict__ wt, const float* __restrict__ bvt, const float* __restrict__ obt,
                        const float* __restrict__ wi, const float* __restrict__ bvi, const float* __restrict__ obi,
                        float* __restrict__ bc){
  int bid = blockIdx.x;
  int tid = threadIdx.x;
  if (bid >= 6656) { addcvt_block(bid - 6656, tid, ta, tb, so); return; }
  if (bid < 3072) {
    int z = bid >> 10, b = bid & 1023;
    const float* in = (z==0) ? c0s : ((z==1) ? c1s : c2s);
    short* out      = (z==0) ? c0d : ((z==1) ? c1d : c2d);
    long i = (long)b*256 + tid;
    f32x4 v = ((const f32x4*)in)[i];
    s16x4 r;
    #pragma unroll
    for (int j=0;j<4;j++) r[j] = f2bf(v[j]);
    *(s16x4*)(out + i*4) = r;
  } else if (bid < 6144) {
    int q = bid - 3072;
    int z = q >> 10, b = q & 1023;
    const float* in = (z==0) ? t0s : ((z==1) ? t1s : t2s);
    short* out      = (z==0) ? t0d : ((z==1) ? t1d : t2d);
    __shared__ float tile[32][33];
    int tx = tid & 31, ty = tid >> 5;
    int c0 = (b & 31)*32, r0 = (b >> 5)*32;
    #pragma unroll
    for (int i=ty; i<32; i+=8)
      tile[i][tx] = in[(long)(r0+i)*1024 + c0 + tx];
    __syncthreads();
    #pragma unroll
    for (int i=ty; i<32; i+=8)
      out[(long)(c0+i)*1024 + r0 + tx] = f2bf(tile[tx][i]);
  } else {
    int q = bid - 6144;
    int z = q >> 8, b = q & 255;
    const float* w  = z ? wi  : wt;
    const float* bv = z ? bvi : bvt;
    const float* ob = z ? obi : obt;
    int n = b*4 + (tid>>6);
    int lane = tid & 63;
    const float* row = w + (long)n*1024;
    float acc = 0.f;
    for (int j=lane; j<1024; j+=64) acc += row[j]*bv[j];
    #pragma unroll
    for (int m=32;m;m>>=1) acc += __shfl_xor(acc, m, 64);
    if (lane==0) bc[z*1024+n] = acc + ob[n];
  }
}

#define GLDS(src, dst) __builtin_amdgcn_global_load_lds( \
    (const __attribute__((address_space(1))) void*)(src), \
    (__attribute__((address_space(3))) void*)(dst), 16, 0, 0)

// ---------- small NT GEMM body (128x128 tile, m97 structure): C bf16 = A@B^T ----------
__device__ __forceinline__
void gemm_small_body(const short* __restrict__ A, const short* __restrict__ B,
                     short* __restrict__ C, int N, int K, int m0, int n0,
                     short* ldsA, short* ldsB, int tid)
{
  const int lane = tid & 63;
  const int wv = tid >> 6;
  const int wm = wv >> 1, wn = wv & 1;

  f32x4 acc[4][4];
  #pragma unroll
  for (int i=0;i<4;i++)
    #pragma unroll
    for (int j=0;j<4;j++) acc[i][j] = (f32x4){0.f,0.f,0.f,0.f};

  const int bo0 = wv*1024 + lane*16;
  const int bo1 = bo0 + 4096;
  const int r0 = bo0 >> 6, c0 = bo0 & 63;
  const int r1 = bo1 >> 6, c1 = bo1 & 63;
  const long rsb = (long)K * 2;

  const char* Ab = (const char*)A;
  const char* Bb = (const char*)B;
  char* lA = (char*)ldsA;
  char* lB = (char*)ldsB;

  const int nkt = K >> 5;
  for (int kt = 0; kt < nkt; ++kt) {
    const long kb = (long)kt * 64;
    GLDS(Ab + (long)(m0 + r0)*rsb + kb + c0, lA + wv*1024);
    GLDS(Ab + (long)(m0 + r1)*rsb + kb + c1, lA + 4096 + wv*1024);
    GLDS(Bb + (long)(n0 + r0)*rsb + kb + c0, lB + wv*1024);
    GLDS(Bb + (long)(n0 + r1)*rsb + kb + c1, lB + 4096 + wv*1024);
    __syncthreads();

    s16x8 af[4], bfv[4];
    #pragma unroll
    for (int i=0;i<4;i++)
      af[i] = *(const s16x8*)(lA + (wm*64 + i*16 + (lane&15))*64 + (lane>>4)*16);
    #pragma unroll
    for (int j=0;j<4;j++)
      bfv[j] = *(const s16x8*)(lB + (wn*64 + j*16 + (lane&15))*64 + (lane>>4)*16);

    #pragma unroll
    for (int i=0;i<4;i++)
      #pragma unroll
      for (int j=0;j<4;j++)
        acc[i][j] = __builtin_amdgcn_mfma_f32_16x16x32_bf16(af[i], bfv[j], acc[i][j], 0, 0, 0);
    __syncthreads();
  }

  #pragma unroll
  for (int j=0;j<4;j++){
    int gn = n0 + wn*64 + j*16 + (lane&15);
    #pragma unroll
    for (int i=0;i<4;i++){
      int gmb = m0 + wm*64 + i*16 + ((lane>>4)*4);
      #pragma unroll
      for (int r=0;r<4;r++)
        C[(long)(gmb+r)*N + gn] = f2bf(acc[i][j][r]);
    }
  }
}

// ---------- L2: gemm_wc (blocks 0..127) + addcvt chunk (128..3127) ----------
__global__ __launch_bounds__(256, 2)
void k_wc_add(const short* __restrict__ Abase, const short* __restrict__ Bbase,
              short* __restrict__ Cbase, long zA, long zB, long zC,
              const float* __restrict__ ta, const float* __restrict__ tb,
              short* __restrict__ so)
{
  __shared__ __align__(16) short ldsA[128*32];
  __shared__ __align__(16) short ldsB[128*32];
  int bid = blockIdx.x;
  if (bid >= 128) { addcvt_block(2600 + bid - 128, threadIdx.x, ta, tb, so); return; }
  int z = bid >> 6, y = (bid >> 3) & 7, x = bid & 7;
  gemm_small_body(Abase + (long)z*zA, Bbase + (long)z*zB, Cbase + (long)z*zC,
                  1024, 1024, x*128, y*128, ldsA, ldsB, threadIdx.x);
}

// ---------- L3: bias2+copy (0..515) + W2 GEMM (516..643) + addcvt (644..3235) ----------
__global__ __launch_bounds__(256, 2)
void k_b2g2(const short* __restrict__ Wc, const float* __restrict__ fuse_b,
            const float* __restrict__ bc, float* __restrict__ b_all,
            const short* __restrict__ fuse_wT, short* __restrict__ W2,
            const float* __restrict__ ta, const float* __restrict__ tb,
            short* __restrict__ so)
{
  __shared__ __align__(16) short ldsA[128*32];
  __shared__ __align__(16) short ldsB[128*32];
  int bid = blockIdx.x;
  if (bid >= 644) { addcvt_block(5600 + bid - 644, threadIdx.x, ta, tb, so); return; }
  if (bid < 512) {
    int n = bid*4 + (threadIdx.x>>6);
    int lane = threadIdx.x & 63;
    const short* row = Wc + (long)n*1024;
    float acc = 0.f;
    for (int j=lane; j<1024; j+=64) acc += bf2f(row[j])*fuse_b[j];
    #pragma unroll
    for (int m=32;m;m>>=1) acc += __shfl_xor(acc, m, 64);
    if (lane==0) b_all[1024+n] = acc + bc[n];
    return;
  }
  if (bid < 516) {
    int i = (bid - 512)*256 + threadIdx.x;
    b_all[i] = fuse_b[i];
    return;
  }
  int g = bid - 516;                 // 0..127 -> 16 x 8 tiles of 2048x1024
  gemm_small_body(Wc, fuse_wT, W2, 1024, 1024,
                  (g & 15)*128, (g >> 4)*128, ldsA, ldsB, threadIdx.x);
}

// ---------- main NT GEMM: 256x256, BK=64, R7 schedule + zero-VALU addressing ----------
// (byte-identical to R13's verified kernel — schedule invariants in R6/R7 notes)
#define MFMA16 __builtin_amdgcn_mfma_f32_16x16x32_bf16
#define VMW4 asm volatile("s_waitcnt vmcnt(4)" ::: "memory")
#define VMW0 asm volatile("s_waitcnt vmcnt(0)" ::: "memory")
#define LGKM0 asm volatile("s_waitcnt lgkmcnt(0)" ::: "memory")
#define MEMF asm volatile("" ::: "memory")

__global__ __launch_bounds__(512, 2)
void gemm_main(const short* __restrict__ A, const short* __restrict__ B,
               float* __restrict__ O, const float* __restrict__ bias,
               int M, int N)
{
  __shared__ __align__(16) char lds[131072];
  constexpr int K = 1024;
  constexpr int nkt = 16;

  const int nbn = N >> 8;
  const int nwg = (M >> 8) * nbn;
  const int cpx = nwg >> 3;
  int bid = blockIdx.x;
  int swz = (bid & 7) * cpx + (bid >> 3);
  const int m0 = (swz / nbn) << 8;
  const int n0 = (swz % nbn) << 8;

  const int tid  = threadIdx.x;
  const int lane = tid & 63;
  const int wid  = tid >> 6;
  const int wm   = wid >> 2;   // 0..1
  const int wn   = wid & 3;    // 0..3
  const long rsb = (long)K * 2;

  f32x4 acc[8][4];
  #pragma unroll
  for (int i=0;i<8;i++)
    #pragma unroll
    for (int j=0;j<4;j++) acc[i][j] = (f32x4){0.f,0.f,0.f,0.f};

  // ---- precomputed LDS read bases (zero per-read VALU) ----
  const int lo0 = (((lane>>4)<<4)) ^ ((lane&7)<<4);
  const int lo1 = lo0 ^ 64;
  const char* pA0 = lds + wm*16384 + (lane&15)*128 + lo0;          // A, ks=0
  const char* pA1 = lds + wm*16384 + (lane&15)*128 + lo1;          // A, ks=1
  const char* pB0 = lds + 65536 + wn*8192 + (lane&15)*128 + lo0;   // B, ks=0
  const char* pB1 = lds + 65536 + wn*8192 + (lane&15)*128 + lo1;   // B, ks=1

  // ---- stage destinations (wave-uniform) + running source pointers ----
  int sdst[2][2];
  const char* Apt[2][2];
  const char* Bpt[2][2];
  #pragma unroll
  for (int H=0;H<2;H++)
    #pragma unroll
    for (int sb=0;sb<2;sb++){
      int c = H*1024 + sb*512 + wid*64 + lane;
      int q = c ^ ((c>>3)&7);
      sdst[H][sb] = (H*1024 + sb*512 + wid*64) << 4;
      const long roff = (long)(q >> 3) * rsb + ((q & 7) << 4);
      Apt[H][sb] = (const char*)A + (long)m0*rsb + roff + 128;  // first use kt=1
      Bpt[H][sb] = (const char*)B + (long)n0*rsb + roff + 256;  // first use kt=2
    }

  // Prologue: A(0)->Abuf0, B(0)->Bbuf0, B(1)->Bbuf1 (12 loads); VMW4 leaves
  // B(1)x4 in flight (drained at ks1(0) VMW0).
  #pragma unroll
  for (int H=0;H<2;H++)
    #pragma unroll
    for (int sb=0;sb<2;sb++)
      GLDS(Apt[H][sb] - 128, lds + sdst[H][sb]);
  #pragma unroll
  for (int H=0;H<2;H++)
    #pragma unroll
    for (int sb=0;sb<2;sb++)
      GLDS(Bpt[H][sb] - 256, lds + 65536 + sdst[H][sb]);
  #pragma unroll
  for (int H=0;H<2;H++)
    #pragma unroll
    for (int sb=0;sb<2;sb++)
      GLDS(Bpt[H][sb] - 128, lds + 98304 + sdst[H][sb]);
  VMW4; MEMF;
  __builtin_amdgcn_s_barrier();

  s16x8 bfr[4][2];
  s16x8 af[8];

  #pragma unroll
  for (int t = 0; t < nkt; ++t) {
    const int RB = (t & 1) << 15;               // compile-time per iteration
    // -------- ks0 phase --------
    #pragma unroll
    for (int j=0;j<4;j++){
      bfr[j][0] = *(const s16x8*)(pB0 + RB + j*2048);
      bfr[j][1] = *(const s16x8*)(pB1 + RB + j*2048);
    }
    #pragma unroll
    for (int i=0;i<8;i++) af[i] = *(const s16x8*)(pA0 + RB + i*2048);
    VMW4; MEMF;
    __builtin_amdgcn_s_barrier();
    if (t+1 < nkt) {
      const int AB2 = ((t+1)&1) << 15;          // compile-time
      #pragma unroll
      for (int H=0;H<2;H++)
        #pragma unroll
        for (int sb=0;sb<2;sb++){
          GLDS(Apt[H][sb], lds + AB2 + sdst[H][sb]);
          Apt[H][sb] += 128;
        }
    }
    LGKM0;
    __builtin_amdgcn_s_setprio(1);
    #pragma unroll
    for (int i=0;i<8;i++)
      #pragma unroll
      for (int j=0;j<4;j++)
        acc[i][j] = MFMA16(af[i], bfr[j][0], acc[i][j], 0, 0, 0);
    __builtin_amdgcn_s_setprio(0);
    // -------- ks1 phase --------
    #pragma unroll
    for (int i=0;i<8;i++) af[i] = *(const s16x8*)(pA1 + RB + i*2048);
    VMW0; MEMF;            // drains B(t+1) AND A(t+1) before the barrier
    __builtin_amdgcn_s_barrier();
    if (t+2 < nkt) {
      const int BB2 = 65536 + RB;               // compile-time
      #pragma unroll
      for (int H=0;H<2;H++)
        #pragma unroll
        for (int sb=0;sb<2;sb++){
          GLDS(Bpt[H][sb], lds + BB2 + sdst[H][sb]);
          Bpt[H][sb] += 128;
        }
    }
    LGKM0;
    __builtin_amdgcn_s_setprio(1);
    #pragma unroll
    for (int i=0;i<8;i++)
      #pragma unroll
      for (int j=0;j<4;j++)
        acc[i][j] = MFMA16(af[i], bfr[j][1], acc[i][j], 0, 0, 0);
    __builtin_amdgcn_s_setprio(0);
  }

  // Epilogue: fp32 + bias, scatter by output region (text | image | fused).
  const long BD = (long)M * 1024L;
  #pragma unroll
  for (int j=0;j<4;j++){
    int gn = n0 + wn*64 + j*16 + (lane&15);
    float bb = bias[gn];
    int region = gn >> 10;
    long rbase = (region==0) ? 2*BD : ((region==1) ? 0L : BD);
    int col = gn & 1023;
    #pragma unroll
    for (int i=0;i<8;i++){
      int gr = m0 + wm*128 + i*16 + ((lane>>4)<<2);
      #pragma unroll
      for (int r=0;r<4;r++)
        O[rbase + (long)(gr+r)*1024 + col] = acc[i][j][r] + bb;
    }
  }
}

extern "C" void kernel_launch(void* const* d_in, const int* in_sizes, int n_in,
                              void* d_out, int out_size, void* d_ws, size_t ws_size,
                              hipStream_t stream) {
  const float* text    = (const float*)d_in[0];
  const float* image   = (const float*)d_in[1];
  const float* fuse_w  = (const float*)d_in[2];
  const float* fuse_b  = (const float*)d_in[3];
  const float* t_in_w  = (const float*)d_in[4];
  const float* t_in_b  = (const float*)d_in[5];
  const float* t_out_w = (const float*)d_in[6];
  const float* t_out_b = (const float*)d_in[7];
  const float* i_in_w  = (const float*)d_in[8];
  const float* i_in_b  = (const float*)d_in[9];
  const float* i_out_w = (const float*)d_in[10];
  const float* i_out_b = (const float*)d_in[11];
  float* out = (float*)d_out;

  const long DD = 1024L*1024L;
  char* ws = (char*)d_ws;
  short* s_bf    = (short*)ws; ws += 16384L*1024*2;
  short* W_all   = (short*)ws; ws += 3*DD*2;      // rows: [fuse_w; Wt2; Wi2]
  short* wvT     = (short*)ws; ws += 2*DD*2;      // [wvT_t; wvT_i]
  short* fuse_wT = (short*)ws; ws += DD*2;
  short* outw_st = (short*)ws; ws += 2*DD*2;      // [t_out_w; i_out_w] bf16
  short* Wc_st   = (short*)ws; ws += 2*DD*2;      // [Wc_t; Wc_i]
  float* bc      = (float*)ws; ws += 2048*4;
  float* b_all   = (float*)ws; ws += 3072*4;

  // L1: weight prep + addcvt[0..2600)
  k_prep1<<<9256, 256, 0, stream>>>(text, image, s_bf,
                                    fuse_w, W_all,
                                    t_out_w, outw_st,
                                    i_out_w, outw_st + DD,
                                    t_in_w + 2*DD, wvT,
                                    i_in_w + 2*DD, wvT + DD,
                                    fuse_w, fuse_wT,
                                    t_out_w, t_in_b + 2048, t_out_b,
                                    i_out_w, i_in_b + 2048, i_out_b, bc);

  // L2: Wc_z = out_w_z @ wv_z + addcvt[2600..5600)
  k_wc_add<<<3128, 256, 0, stream>>>(outw_st, wvT, Wc_st, DD, DD, DD,
                                     text, image, s_bf);

  // L3: b_all = [fuse_b ; Wc@fuse_b + bc], W2 = Wc @ fuse_w, addcvt[5600..8192)
  k_b2g2<<<3236, 256, 0, stream>>>(Wc_st, fuse_b, bc, b_all, fuse_wT, W_all + DD,
                                   text, image, s_bf);

  // L4: main C = s @ W_all.T + b_all, scatter into d_out
  gemm_main<<<dim3(768), 512, 0, stream>>>(s_bf, W_all, out, b_all, 16384, 3072);
}

// Round 15
// 181.023 us; speedup vs baseline: 1.2005x; 1.0812x over previous
//
#include <hip/hip_runtime.h>
#include <stdint.h>

typedef float f32x4 __attribute__((ext_vector_type(4)));
typedef short s16x8 __attribute__((ext_vector_type(8)));
typedef short s16x4 __attribute__((ext_vector_type(4)));

__device__ __forceinline__ short f2bf(float f){
  union { float f; unsigned u; } v; v.f = f;
  unsigned r = v.u + 0x7FFFu + ((v.u >> 16) & 1u);
  return (short)(r >> 16);
}
__device__ __forceinline__ float bf2f(short h){
  union { unsigned u; float f; } v; v.u = ((unsigned)(unsigned short)h) << 16;
  return v.f;
}

// ---------- addcvt block: s_bf[gbid] = bf16(text+image), gbid in [0,8192) ----------
__device__ __forceinline__
void addcvt_block(int gbid, int tid, const float* __restrict__ ta,
                  const float* __restrict__ tb, short* __restrict__ so){
  long i = (long)gbid * 256 + tid;
  const f32x4* a4 = (const f32x4*)ta;
  const f32x4* b4 = (const f32x4*)tb;
  f32x4 x0 = a4[2*i], x1 = a4[2*i+1];
  f32x4 y0 = b4[2*i], y1 = b4[2*i+1];
  s16x8 r;
  #pragma unroll
  for (int j=0;j<4;j++){ r[j] = f2bf(x0[j]+y0[j]); r[j+4] = f2bf(x1[j]+y1[j]); }
  *(s16x8*)(so + i*8) = r;
}

// ---------- L1: weight prep (blocks 0..6655) + addcvt chunk (6656..9947) ----------
__global__ void k_prep1(const float* __restrict__ ta, const float* __restrict__ tb,
                        short* __restrict__ so,
                        const float* __restrict__ c0s, short* __restrict__ c0d,
                        const float* __restrict__ c1s, short* __restrict__ c1d,
                        const float* __restrict__ c2s, short* __restrict__ c2d,
                        const float* __restrict__ t0s, short* __restrict__ t0d,
                        const float* __restrict__ t1s, short* __restrict__ t1d,
                        const float* __restrict__ t2s, short* __restrict__ t2d,
                        const float* __restrict__ wt, const float* __restrict__ bvt, const float* __restrict__ obt,
                        const float* __restrict__ wi, const float* __restrict__ bvi, const float* __restrict__ obi,
                        float* __restrict__ bc){
  int bid = blockIdx.x;
  int tid = threadIdx.x;
  if (bid >= 6656) { addcvt_block(bid - 6656, tid, ta, tb, so); return; }
  if (bid < 3072) {
    int z = bid >> 10, b = bid & 1023;
    const float* in = (z==0) ? c0s : ((z==1) ? c1s : c2s);
    short* out      = (z==0) ? c0d : ((z==1) ? c1d : c2d);
    long i = (long)b*256 + tid;
    f32x4 v = ((const f32x4*)in)[i];
    s16x4 r;
    #pragma unroll
    for (int j=0;j<4;j++) r[j] = f2bf(v[j]);
    *(s16x4*)(out + i*4) = r;
  } else if (bid < 6144) {
    int q = bid - 3072;
    int z = q >> 10, b = q & 1023;
    const float* in = (z==0) ? t0s : ((z==1) ? t1s : t2s);
    short* out      = (z==0) ? t0d : ((z==1) ? t1d : t2d);
    __shared__ float tile[32][33];
    int tx = tid & 31, ty = tid >> 5;
    int c0 = (b & 31)*32, r0 = (b >> 5)*32;
    #pragma unroll
    for (int i=ty; i<32; i+=8)
      tile[i][tx] = in[(long)(r0+i)*1024 + c0 + tx];
    __syncthreads();
    #pragma unroll
    for (int i=ty; i<32; i+=8)
      out[(long)(c0+i)*1024 + r0 + tx] = f2bf(tile[tx][i]);
  } else {
    int q = bid - 6144;
    int z = q >> 8, b = q & 255;
    const float* w  = z ? wi  : wt;
    const float* bv = z ? bvi : bvt;
    const float* ob = z ? obi : obt;
    int n = b*4 + (tid>>6);
    int lane = tid & 63;
    const float* row = w + (long)n*1024;
    float acc = 0.f;
    for (int j=lane; j<1024; j+=64) acc += row[j]*bv[j];
    #pragma unroll
    for (int m=32;m;m>>=1) acc += __shfl_xor(acc, m, 64);
    if (lane==0) bc[z*1024+n] = acc + ob[n];
  }
}

#define GLDS(src, dst) __builtin_amdgcn_global_load_lds( \
    (const __attribute__((address_space(1))) void*)(src), \
    (__attribute__((address_space(3))) void*)(dst), 16, 0, 0)

// ---------- small NT GEMM body (128x128 tile, m97 structure): C bf16 = A@B^T ----------
__device__ __forceinline__
void gemm_small_body(const short* __restrict__ A, const short* __restrict__ B,
                     short* __restrict__ C, int N, int K, int m0, int n0,
                     short* ldsA, short* ldsB, int tid)
{
  const int lane = tid & 63;
  const int wv = tid >> 6;
  const int wm = wv >> 1, wn = wv & 1;

  f32x4 acc[4][4];
  #pragma unroll
  for (int i=0;i<4;i++)
    #pragma unroll
    for (int j=0;j<4;j++) acc[i][j] = (f32x4){0.f,0.f,0.f,0.f};

  const int bo0 = wv*1024 + lane*16;
  const int bo1 = bo0 + 4096;
  const int r0 = bo0 >> 6, c0 = bo0 & 63;
  const int r1 = bo1 >> 6, c1 = bo1 & 63;
  const long rsb = (long)K * 2;

  const char* Ab = (const char*)A;
  const char* Bb = (const char*)B;
  char* lA = (char*)ldsA;
  char* lB = (char*)ldsB;

  const int nkt = K >> 5;
  for (int kt = 0; kt < nkt; ++kt) {
    const long kb = (long)kt * 64;
    GLDS(Ab + (long)(m0 + r0)*rsb + kb + c0, lA + wv*1024);
    GLDS(Ab + (long)(m0 + r1)*rsb + kb + c1, lA + 4096 + wv*1024);
    GLDS(Bb + (long)(n0 + r0)*rsb + kb + c0, lB + wv*1024);
    GLDS(Bb + (long)(n0 + r1)*rsb + kb + c1, lB + 4096 + wv*1024);
    __syncthreads();

    s16x8 af[4], bfv[4];
    #pragma unroll
    for (int i=0;i<4;i++)
      af[i] = *(const s16x8*)(lA + (wm*64 + i*16 + (lane&15))*64 + (lane>>4)*16);
    #pragma unroll
    for (int j=0;j<4;j++)
      bfv[j] = *(const s16x8*)(lB + (wn*64 + j*16 + (lane&15))*64 + (lane>>4)*16);

    #pragma unroll
    for (int i=0;i<4;i++)
      #pragma unroll
      for (int j=0;j<4;j++)
        acc[i][j] = __builtin_amdgcn_mfma_f32_16x16x32_bf16(af[i], bfv[j], acc[i][j], 0, 0, 0);
    __syncthreads();
  }

  #pragma unroll
  for (int j=0;j<4;j++){
    int gn = n0 + wn*64 + j*16 + (lane&15);
    #pragma unroll
    for (int i=0;i<4;i++){
      int gmb = m0 + wm*64 + i*16 + ((lane>>4)*4);
      #pragma unroll
      for (int r=0;r<4;r++)
        C[(long)(gmb+r)*N + gn] = f2bf(acc[i][j][r]);
    }
  }
}

// ---------- L2: gemm_wc (blocks 0..127) + addcvt chunk (128..2427) ----------
__global__ __launch_bounds__(256, 2)
void k_wc_add(const short* __restrict__ Abase, const short* __restrict__ Bbase,
              short* __restrict__ Cbase, long zA, long zB, long zC,
              const float* __restrict__ ta, const float* __restrict__ tb,
              short* __restrict__ so)
{
  __shared__ __align__(16) short ldsA[128*32];
  __shared__ __align__(16) short ldsB[128*32];
  int bid = blockIdx.x;
  if (bid >= 128) { addcvt_block(3292 + bid - 128, threadIdx.x, ta, tb, so); return; }
  int z = bid >> 6, y = (bid >> 3) & 7, x = bid & 7;
  gemm_small_body(Abase + (long)z*zA, Bbase + (long)z*zB, Cbase + (long)z*zC,
                  1024, 1024, x*128, y*128, ldsA, ldsB, threadIdx.x);
}

// ---------- L3: bias2+copy (0..515) + W2 GEMM (516..643) + addcvt (644..3243) ----------
__global__ __launch_bounds__(256, 2)
void k_b2g2(const short* __restrict__ Wc, const float* __restrict__ fuse_b,
            const float* __restrict__ bc, float* __restrict__ b_all,
            const short* __restrict__ fuse_wT, short* __restrict__ W2,
            const float* __restrict__ ta, const float* __restrict__ tb,
            short* __restrict__ so)
{
  __shared__ __align__(16) short ldsA[128*32];
  __shared__ __align__(16) short ldsB[128*32];
  int bid = blockIdx.x;
  if (bid >= 644) { addcvt_block(5592 + bid - 644, threadIdx.x, ta, tb, so); return; }
  if (bid < 512) {
    int n = bid*4 + (threadIdx.x>>6);
    int lane = threadIdx.x & 63;
    const short* row = Wc + (long)n*1024;
    float acc = 0.f;
    for (int j=lane; j<1024; j+=64) acc += bf2f(row[j])*fuse_b[j];
    #pragma unroll
    for (int m=32;m;m>>=1) acc += __shfl_xor(acc, m, 64);
    if (lane==0) b_all[1024+n] = acc + bc[n];
    return;
  }
  if (bid < 516) {
    int i = (bid - 512)*256 + threadIdx.x;
    b_all[i] = fuse_b[i];
    return;
  }
  int g = bid - 516;                 // 0..127 -> 16 x 8 tiles of 2048x1024
  gemm_small_body(Wc, fuse_wT, W2, 1024, 1024,
                  (g & 15)*128, (g >> 4)*128, ldsA, ldsB, threadIdx.x);
}

// ---------- main NT GEMM: 256x256, BK=64, R7 schedule + zero-VALU addressing ----------
// (R13-verified; R15 adds non-temporal output stores — C is never re-read, so
// bypassing L2 preserves the A/B panel working set that FETCH shows is served
// from L2/L3. Schedule invariants in R6/R7 notes.)
#define MFMA16 __builtin_amdgcn_mfma_f32_16x16x32_bf16
#define VMW4 asm volatile("s_waitcnt vmcnt(4)" ::: "memory")
#define VMW0 asm volatile("s_waitcnt vmcnt(0)" ::: "memory")
#define LGKM0 asm volatile("s_waitcnt lgkmcnt(0)" ::: "memory")
#define MEMF asm volatile("" ::: "memory")

__global__ __launch_bounds__(512, 2)
void gemm_main(const short* __restrict__ A, const short* __restrict__ B,
               float* __restrict__ O, const float* __restrict__ bias,
               int M, int N)
{
  __shared__ __align__(16) char lds[131072];
  constexpr int K = 1024;
  constexpr int nkt = 16;

  const int nbn = N >> 8;
  const int nwg = (M >> 8) * nbn;
  const int cpx = nwg >> 3;
  int bid = blockIdx.x;
  int swz = (bid & 7) * cpx + (bid >> 3);
  const int m0 = (swz / nbn) << 8;
  const int n0 = (swz % nbn) << 8;

  const int tid  = threadIdx.x;
  const int lane = tid & 63;
  const int wid  = tid >> 6;
  const int wm   = wid >> 2;   // 0..1
  const int wn   = wid & 3;    // 0..3
  const long rsb = (long)K * 2;

  f32x4 acc[8][4];
  #pragma unroll
  for (int i=0;i<8;i++)
    #pragma unroll
    for (int j=0;j<4;j++) acc[i][j] = (f32x4){0.f,0.f,0.f,0.f};

  // ---- precomputed LDS read bases (zero per-read VALU) ----
  const int lo0 = (((lane>>4)<<4)) ^ ((lane&7)<<4);
  const int lo1 = lo0 ^ 64;
  const char* pA0 = lds + wm*16384 + (lane&15)*128 + lo0;          // A, ks=0
  const char* pA1 = lds + wm*16384 + (lane&15)*128 + lo1;          // A, ks=1
  const char* pB0 = lds + 65536 + wn*8192 + (lane&15)*128 + lo0;   // B, ks=0
  const char* pB1 = lds + 65536 + wn*8192 + (lane&15)*128 + lo1;   // B, ks=1

  // ---- stage destinations (wave-uniform) + running source pointers ----
  int sdst[2][2];
  const char* Apt[2][2];
  const char* Bpt[2][2];
  #pragma unroll
  for (int H=0;H<2;H++)
    #pragma unroll
    for (int sb=0;sb<2;sb++){
      int c = H*1024 + sb*512 + wid*64 + lane;
      int q = c ^ ((c>>3)&7);
      sdst[H][sb] = (H*1024 + sb*512 + wid*64) << 4;
      const long roff = (long)(q >> 3) * rsb + ((q & 7) << 4);
      Apt[H][sb] = (const char*)A + (long)m0*rsb + roff + 128;  // first use kt=1
      Bpt[H][sb] = (const char*)B + (long)n0*rsb + roff + 256;  // first use kt=2
    }

  // Prologue: A(0)->Abuf0, B(0)->Bbuf0, B(1)->Bbuf1 (12 loads); VMW4 leaves
  // B(1)x4 in flight (drained at ks1(0) VMW0).
  #pragma unroll
  for (int H=0;H<2;H++)
    #pragma unroll
    for (int sb=0;sb<2;sb++)
      GLDS(Apt[H][sb] - 128, lds + sdst[H][sb]);
  #pragma unroll
  for (int H=0;H<2;H++)
    #pragma unroll
    for (int sb=0;sb<2;sb++)
      GLDS(Bpt[H][sb] - 256, lds + 65536 + sdst[H][sb]);
  #pragma unroll
  for (int H=0;H<2;H++)
    #pragma unroll
    for (int sb=0;sb<2;sb++)
      GLDS(Bpt[H][sb] - 128, lds + 98304 + sdst[H][sb]);
  VMW4; MEMF;
  __builtin_amdgcn_s_barrier();

  s16x8 bfr[4][2];
  s16x8 af[8];

  #pragma unroll
  for (int t = 0; t < nkt; ++t) {
    const int RB = (t & 1) << 15;               // compile-time per iteration
    // -------- ks0 phase --------
    #pragma unroll
    for (int j=0;j<4;j++){
      bfr[j][0] = *(const s16x8*)(pB0 + RB + j*2048);
      bfr[j][1] = *(const s16x8*)(pB1 + RB + j*2048);
    }
    #pragma unroll
    for (int i=0;i<8;i++) af[i] = *(const s16x8*)(pA0 + RB + i*2048);
    VMW4; MEMF;
    __builtin_amdgcn_s_barrier();
    if (t+1 < nkt) {
      const int AB2 = ((t+1)&1) << 15;          // compile-time
      #pragma unroll
      for (int H=0;H<2;H++)
        #pragma unroll
        for (int sb=0;sb<2;sb++){
          GLDS(Apt[H][sb], lds + AB2 + sdst[H][sb]);
          Apt[H][sb] += 128;
        }
    }
    LGKM0;
    __builtin_amdgcn_s_setprio(1);
    #pragma unroll
    for (int i=0;i<8;i++)
      #pragma unroll
      for (int j=0;j<4;j++)
        acc[i][j] = MFMA16(af[i], bfr[j][0], acc[i][j], 0, 0, 0);
    __builtin_amdgcn_s_setprio(0);
    // -------- ks1 phase --------
    #pragma unroll
    for (int i=0;i<8;i++) af[i] = *(const s16x8*)(pA1 + RB + i*2048);
    VMW0; MEMF;            // drains B(t+1) AND A(t+1) before the barrier
    __builtin_amdgcn_s_barrier();
    if (t+2 < nkt) {
      const int BB2 = 65536 + RB;               // compile-time
      #pragma unroll
      for (int H=0;H<2;H++)
        #pragma unroll
        for (int sb=0;sb<2;sb++){
          GLDS(Bpt[H][sb], lds + BB2 + sdst[H][sb]);
          Bpt[H][sb] += 128;
        }
    }
    LGKM0;
    __builtin_amdgcn_s_setprio(1);
    #pragma unroll
    for (int i=0;i<8;i++)
      #pragma unroll
      for (int j=0;j<4;j++)
        acc[i][j] = MFMA16(af[i], bfr[j][1], acc[i][j], 0, 0, 0);
    __builtin_amdgcn_s_setprio(0);
  }

  // Epilogue: fp32 + bias, scatter by output region (text | image | fused).
  // Non-temporal stores: output is never re-read; don't evict A/B panels.
  const long BD = (long)M * 1024L;
  #pragma unroll
  for (int j=0;j<4;j++){
    int gn = n0 + wn*64 + j*16 + (lane&15);
    float bb = bias[gn];
    int region = gn >> 10;
    long rbase = (region==0) ? 2*BD : ((region==1) ? 0L : BD);
    int col = gn & 1023;
    #pragma unroll
    for (int i=0;i<8;i++){
      int gr = m0 + wm*128 + i*16 + ((lane>>4)<<2);
      #pragma unroll
      for (int r=0;r<4;r++)
        __builtin_nontemporal_store(acc[i][j][r] + bb,
                                    &O[rbase + (long)(gr+r)*1024 + col]);
    }
  }
}

extern "C" void kernel_launch(void* const* d_in, const int* in_sizes, int n_in,
                              void* d_out, int out_size, void* d_ws, size_t ws_size,
                              hipStream_t stream) {
  const float* text    = (const float*)d_in[0];
  const float* image   = (const float*)d_in[1];
  const float* fuse_w  = (const float*)d_in[2];
  const float* fuse_b  = (const float*)d_in[3];
  const float* t_in_w  = (const float*)d_in[4];
  const float* t_in_b  = (const float*)d_in[5];
  const float* t_out_w = (const float*)d_in[6];
  const float* t_out_b = (const float*)d_in[7];
  const float* i_in_w  = (const float*)d_in[8];
  const float* i_in_b  = (const float*)d_in[9];
  const float* i_out_w = (const float*)d_in[10];
  const float* i_out_b = (const float*)d_in[11];
  float* out = (float*)d_out;

  const long DD = 1024L*1024L;
  char* ws = (char*)d_ws;
  short* s_bf    = (short*)ws; ws += 16384L*1024*2;
  short* W_all   = (short*)ws; ws += 3*DD*2;      // rows: [fuse_w; Wt2; Wi2]
  short* wvT     = (short*)ws; ws += 2*DD*2;      // [wvT_t; wvT_i]
  short* fuse_wT = (short*)ws; ws += DD*2;
  short* outw_st = (short*)ws; ws += 2*DD*2;      // [t_out_w; i_out_w] bf16
  short* Wc_st   = (short*)ws; ws += 2*DD*2;      // [Wc_t; Wc_i]
  float* bc      = (float*)ws; ws += 2048*4;
  float* b_all   = (float*)ws; ws += 3072*4;

  // L1: weight prep + addcvt[0..3292)
  k_prep1<<<9948, 256, 0, stream>>>(text, image, s_bf,
                                    fuse_w, W_all,
                                    t_out_w, outw_st,
                                    i_out_w, outw_st + DD,
                                    t_in_w + 2*DD, wvT,
                                    i_in_w + 2*DD, wvT + DD,
                                    fuse_w, fuse_wT,
                                    t_out_w, t_in_b + 2048, t_out_b,
                                    i_out_w, i_in_b + 2048, i_out_b, bc);

  // L2: Wc_z = out_w_z @ wv_z + addcvt[3292..5592)
  k_wc_add<<<2428, 256, 0, stream>>>(outw_st, wvT, Wc_st, DD, DD, DD,
                                     text, image, s_bf);

  // L3: b_all = [fuse_b ; Wc@fuse_b + bc], W2 = Wc @ fuse_w, addcvt[5592..8192)
  k_b2g2<<<3244, 256, 0, stream>>>(Wc_st, fuse_b, bc, b_all, fuse_wT, W_all + DD,
                                   text, image, s_bf);

  // L4: main C = s @ W_all.T + b_all, scatter into d_out
  gemm_main<<<dim3(768), 512, 0, stream>>>(s_bf, W_all, out, b_all, 16384, 3072);
}